// Round 1
// baseline (5494.570 us; speedup 1.0000x reference)
//
#include <hip/hip_runtime.h>
#include <math.h>

// ---------- bf16 helpers ----------
__device__ __forceinline__ float bf2f(unsigned short u){
  return __uint_as_float(((unsigned)u) << 16);
}
__device__ __forceinline__ unsigned short f2bf(float f){
  unsigned v = __float_as_uint(f);
  return (unsigned short)((v + 0x7FFFu + ((v >> 16) & 1u)) >> 16);
}

// ---------- conv 3x3 SAME, fused input-BN+ReLU, fused output stats ----------
// Input layout [B][CIN][400] (float if !BN_IN, bf16 if BN_IN),
// weights OIHW [COUT][CIN][3][3], output y_pre bf16 [B][COUT][400],
// stats[c] += sum(y), stats[COUT+c] += sum(y^2).
template<int CIN, int COUT, int CI_CHUNK, int CO_CHUNK, bool BN_IN>
__global__ __launch_bounds__(256) void conv_kernel(
    const void* __restrict__ xin, const float* __restrict__ ss_in,
    const float* __restrict__ Wt, const float* __restrict__ bconv,
    unsigned short* __restrict__ y_pre, float* __restrict__ stats)
{
  __shared__ float xs[CI_CHUNK][484];  // padded 22x22 per channel
  const int tid = threadIdx.x;
  const int b   = blockIdx.x;
  const int co0 = blockIdx.y * CO_CHUNK;

  float acc0[CO_CHUNK], acc1[CO_CHUNK];
#pragma unroll
  for (int co = 0; co < CO_CHUNK; ++co){ acc0[co] = 0.f; acc1[co] = 0.f; }

  const int p0 = tid;
  const int p1 = tid + 256;
  const bool v1 = (p1 < 400);
  const int h0 = p0 / 20, w0 = p0 - h0 * 20;
  const int p1c = v1 ? p1 : 0;
  const int h1 = p1c / 20, w1 = p1c - h1 * 20;

  float* xflat = &xs[0][0];
  for (int i = tid; i < CI_CHUNK * 484; i += 256) xflat[i] = 0.f;
  __syncthreads();

  for (int cc = 0; cc < CIN; cc += CI_CHUNK){
    // stage interior (borders stay zero)
    for (int i = tid; i < CI_CHUNK * 400; i += 256){
      int ci = i / 400;
      int p  = i - ci * 400;
      int hh = p / 20, ww = p - hh * 20;
      float v;
      if constexpr (BN_IN){
        float raw = bf2f(((const unsigned short*)xin)[((size_t)b * CIN + cc + ci) * 400 + p]);
        v = fmaxf(fmaf(raw, ss_in[cc + ci], ss_in[CIN + cc + ci]), 0.f);
      } else {
        v = ((const float*)xin)[((size_t)b * CIN + cc + ci) * 400 + p];
      }
      xs[ci][(hh + 1) * 22 + (ww + 1)] = v;
    }
    __syncthreads();
    for (int ci = 0; ci < CI_CHUNK; ++ci){
      float x0[9], x1[9];
#pragma unroll
      for (int dh = 0; dh < 3; ++dh)
#pragma unroll
        for (int dw = 0; dw < 3; ++dw){
          x0[dh * 3 + dw] = xs[ci][(h0 + dh) * 22 + (w0 + dw)];
          x1[dh * 3 + dw] = xs[ci][(h1 + dh) * 22 + (w1 + dw)];
        }
      const float* wp = Wt + ((size_t)co0 * CIN + (cc + ci)) * 9;  // uniform -> s_load
#pragma unroll
      for (int co = 0; co < CO_CHUNK; ++co){
        const float* wq = wp + (size_t)co * CIN * 9;
#pragma unroll
        for (int k = 0; k < 9; ++k){
          float wv = wq[k];
          acc0[co] = fmaf(x0[k], wv, acc0[co]);
          acc1[co] = fmaf(x1[k], wv, acc1[co]);
        }
      }
    }
    __syncthreads();
  }

  // epilogue: bias, store bf16, per-channel stats via wave reduce + atomics
#pragma unroll
  for (int co = 0; co < CO_CHUNK; ++co){
    float bias = bconv[co0 + co];
    float y0 = acc0[co] + bias;
    float y1 = acc1[co] + bias;
    size_t base = ((size_t)b * COUT + co0 + co) * 400;
    y_pre[base + p0] = f2bf(y0);
    if (v1) y_pre[base + p1] = f2bf(y1);
    float s = y0 + (v1 ? y1 : 0.f);
    float q = y0 * y0 + (v1 ? y1 * y1 : 0.f);
#pragma unroll
    for (int off = 32; off; off >>= 1){
      s += __shfl_down(s, off);
      q += __shfl_down(q, off);
    }
    if ((tid & 63) == 0){
      atomicAdd(&stats[co0 + co], s);
      atomicAdd(&stats[COUT + co0 + co], q);
    }
  }
}

// ---------- fold stats -> per-channel scale/shift ----------
__global__ void bn_fin(const float* __restrict__ stats, const float* __restrict__ g,
                       const float* __restrict__ be, float* __restrict__ ss,
                       int C, float invN)
{
  int c = threadIdx.x;
  if (c < C){
    float mean = stats[c] * invN;
    float var  = stats[C + c] * invN - mean * mean;
    float sc   = g[c] * rsqrtf(var + 1e-5f);
    ss[c]      = sc;
    ss[C + c]  = be[c] - mean * sc;
  }
}

// ---------- apply BN+ReLU to y4 -> a4 (bf16) ----------
__global__ __launch_bounds__(256) void act4_kernel(const unsigned short* __restrict__ y4,
                                                   const float* __restrict__ ss,
                                                   unsigned short* __restrict__ a4, int n)
{
  int i = blockIdx.x * 256 + threadIdx.x;
  if (i < n){
    int c = (i / 400) & 31;
    float v = fmaf(bf2f(y4[i]), ss[c], ss[32 + c]);
    a4[i] = f2bf(fmaxf(v, 0.f));
  }
}

// ---------- init linear out with bias ----------
__global__ void lin_init(const float* __restrict__ bo, float* __restrict__ lin, int total)
{
  int i = blockIdx.x * 256 + threadIdx.x;
  if (i < total) lin[i] = bo[i % 200];
}

// ---------- linear: lin[b][j] += sum_k a4[b][k] * Wo[j][k], K split 8-way ----------
__global__ __launch_bounds__(256) void linear_kernel(const unsigned short* __restrict__ a4,
                                                     const float* __restrict__ Wo,
                                                     float* __restrict__ lin)
{
  __shared__ float At[64][68];  // [kk][row], +4 pad keeps 16B alignment & kills read conflicts
  __shared__ float Bt[64][68];  // [kk][col]
  const int tid = threadIdx.x;
  const int b0 = blockIdx.x * 64;
  const int j0 = blockIdx.y * 64;
  const int k0 = blockIdx.z * 1600;
  const int rowg = tid & 15;   // rows rowg*4..+3
  const int colg = tid >> 4;   // cols colg*4..+3
  float acc[4][4];
#pragma unroll
  for (int r = 0; r < 4; ++r)
#pragma unroll
    for (int c = 0; c < 4; ++c) acc[r][c] = 0.f;

  for (int kt = k0; kt < k0 + 1600; kt += 64){
    __syncthreads();
    for (int i = tid; i < 4096; i += 256){
      int r = i >> 6, kk = i & 63;
      At[kk][r] = bf2f(a4[(size_t)(b0 + r) * 12800 + kt + kk]);
    }
    for (int i = tid; i < 4096; i += 256){
      int c = i >> 6, kk = i & 63;
      int j = j0 + c;
      Bt[kk][c] = (j < 200) ? Wo[(size_t)j * 12800 + kt + kk] : 0.f;
    }
    __syncthreads();
#pragma unroll 4
    for (int kk = 0; kk < 64; ++kk){
      float4 av = *reinterpret_cast<const float4*>(&At[kk][rowg * 4]);
      float4 bv = *reinterpret_cast<const float4*>(&Bt[kk][colg * 4]);
      float a[4] = {av.x, av.y, av.z, av.w};
      float bb[4] = {bv.x, bv.y, bv.z, bv.w};
#pragma unroll
      for (int r = 0; r < 4; ++r)
#pragma unroll
        for (int c = 0; c < 4; ++c) acc[r][c] = fmaf(a[r], bb[c], acc[r][c]);
    }
  }
#pragma unroll
  for (int r = 0; r < 4; ++r){
    int bb = b0 + rowg * 4 + r;
#pragma unroll
    for (int c = 0; c < 4; ++c){
      int j = j0 + colg * 4 + c;
      if (j < 200) atomicAdd(&lin[(size_t)bb * 200 + j], acc[r][c]);
    }
  }
}

// ---------- phase + einsum + norm ----------
__global__ __launch_bounds__(256) void phase_kernel(const float* __restrict__ lin,
                                                    const float* __restrict__ Gr,
                                                    const float* __restrict__ Gi,
                                                    const float* __restrict__ hrr,
                                                    const float* __restrict__ hri,
                                                    float* __restrict__ accum)
{
  const int b = blockIdx.x;
  const int tid = threadIdx.x;
  __shared__ float u[100];   // c*hr - s*hi
  __shared__ float pp[100];  // c*hi + s*hr
  __shared__ float redbuf[4];
  if (tid < 100){
    float t1 = lin[b * 200 + tid];
    float t2 = lin[b * 200 + 100 + tid];
    float c = cosf(t1);
    float s = sinf(t2);
    float hr = hrr[b * 100 + tid];
    float hi = hri[b * 100 + tid];
    u[tid]  = c * hr - s * hi;
    pp[tid] = c * hi + s * hr;
  }
  __syncthreads();
  // t2r[m] = sum_d Gr*u - Gi*pp ; t2i[m] = sum_d Gr*pp + Gi*u
  const int m = tid;  // M=256
  const float4* grow  = (const float4*)(Gr + ((size_t)b * 256 + m) * 100);
  const float4* girow = (const float4*)(Gi + ((size_t)b * 256 + m) * 100);
  float tr = 0.f, ti = 0.f;
#pragma unroll
  for (int i = 0; i < 25; ++i){
    float4 g  = grow[i];
    float4 gg = girow[i];
    float4 uu = *(const float4*)&u[i * 4];
    float4 qq = *(const float4*)&pp[i * 4];
    tr += g.x * uu.x - gg.x * qq.x;  ti += g.x * qq.x + gg.x * uu.x;
    tr += g.y * uu.y - gg.y * qq.y;  ti += g.y * qq.y + gg.y * uu.y;
    tr += g.z * uu.z - gg.z * qq.z;  ti += g.z * qq.z + gg.z * uu.z;
    tr += g.w * uu.w - gg.w * qq.w;  ti += g.w * qq.w + gg.w * uu.w;
  }
  float ns = tr * tr + ti * ti;
#pragma unroll
  for (int off = 32; off; off >>= 1) ns += __shfl_down(ns, off);
  if ((tid & 63) == 0) redbuf[tid >> 6] = ns;
  __syncthreads();
  if (tid == 0) atomicAdd(accum, redbuf[0] + redbuf[1] + redbuf[2] + redbuf[3]);
}

__global__ void finalize_kernel(const float* __restrict__ accum, float* __restrict__ out)
{
  out[0] = -accum[0] * (1.0f / 512.0f);
}

extern "C" void kernel_launch(void* const* d_in, const int* in_sizes, int n_in,
                              void* d_out, int out_size, void* d_ws, size_t ws_size,
                              hipStream_t stream)
{
  const float* F   = (const float*)d_in[0];
  const float* Gr  = (const float*)d_in[1];
  const float* Gi  = (const float*)d_in[2];
  const float* hrr = (const float*)d_in[3];
  const float* hri = (const float*)d_in[4];
  const float* W1  = (const float*)d_in[5];
  const float* b1  = (const float*)d_in[6];
  const float* g1  = (const float*)d_in[7];
  const float* be1 = (const float*)d_in[8];
  const float* W2  = (const float*)d_in[9];
  const float* b2  = (const float*)d_in[10];
  const float* g2  = (const float*)d_in[11];
  const float* be2 = (const float*)d_in[12];
  const float* W3  = (const float*)d_in[13];
  const float* b3  = (const float*)d_in[14];
  const float* g3  = (const float*)d_in[15];
  const float* be3 = (const float*)d_in[16];
  const float* W4  = (const float*)d_in[17];
  const float* b4  = (const float*)d_in[18];
  const float* g4  = (const float*)d_in[19];
  const float* be4 = (const float*)d_in[20];
  const float* Wo  = (const float*)d_in[21];
  const float* bo  = (const float*)d_in[22];

  char* ws = (char*)d_ws;
  unsigned short* bufA = (unsigned short*)(ws);              // 26,214,400 bf16 = 52,428,800 B
  unsigned short* bufB = (unsigned short*)(ws + 52428800);   // 13,107,200 bf16 = 26,214,400 B
  float* lin   = (float*)(ws + 78643200);                    // 102,400 f32
  float* stats = (float*)(ws + 79052800);                    // 1024 f32 (4 layers x 256)
  float* ssb   = (float*)(ws + 79056896);                    // 1024 f32 (4 layers x 256)
  float* accum = (float*)(ws + 79060992);                    // 1 f32

  // zero stats + (ss, harmless) + accum each call
  hipMemsetAsync(ws + 79052800, 0, 8256, stream);

  const float invN = 1.0f / 204800.0f;  // 512*400

  // conv1: 2 -> 128, raw float input
  conv_kernel<2, 128, 2, 16, false><<<dim3(512, 8), 256, 0, stream>>>(
      (const void*)F, nullptr, W1, b1, bufA, stats);
  bn_fin<<<1, 128, 0, stream>>>(stats, g1, be1, ssb, 128, invN);

  // conv2: 128 -> 64
  conv_kernel<128, 64, 16, 16, true><<<dim3(512, 4), 256, 0, stream>>>(
      (const void*)bufA, ssb, W2, b2, bufB, stats + 256);
  bn_fin<<<1, 64, 0, stream>>>(stats + 256, g2, be2, ssb + 256, 64, invN);

  // conv3: 64 -> 64 (writes back into bufA region)
  conv_kernel<64, 64, 16, 16, true><<<dim3(512, 4), 256, 0, stream>>>(
      (const void*)bufB, ssb + 256, W3, b3, bufA, stats + 512);
  bn_fin<<<1, 64, 0, stream>>>(stats + 512, g3, be3, ssb + 512, 64, invN);

  // conv4: 64 -> 32 (writes into bufB region)
  conv_kernel<64, 32, 16, 16, true><<<dim3(512, 2), 256, 0, stream>>>(
      (const void*)bufA, ssb + 512, W4, b4, bufB, stats + 768);
  bn_fin<<<1, 32, 0, stream>>>(stats + 768, g4, be4, ssb + 768, 32, invN);

  // activate y4 -> a4 (into bufA region)
  act4_kernel<<<25600, 256, 0, stream>>>(bufB, ssb + 768, bufA, 6553600);

  // linear 12800 -> 200
  lin_init<<<400, 256, 0, stream>>>(bo, lin, 102400);
  linear_kernel<<<dim3(8, 4, 8), 256, 0, stream>>>(bufA, Wo, lin);

  // phase + norm
  phase_kernel<<<512, 256, 0, stream>>>(lin, Gr, Gi, hrr, hri, accum);
  finalize_kernel<<<1, 1, 0, stream>>>(accum, (float*)d_out);
}

// Round 2
// 1063.189 us; speedup vs baseline: 5.1680x; 5.1680x over previous
//
#include <hip/hip_runtime.h>
#include <math.h>

typedef __bf16 bf16x8 __attribute__((ext_vector_type(8)));
typedef float f32x4 __attribute__((ext_vector_type(4)));
typedef unsigned short ushort8 __attribute__((ext_vector_type(8)));

__device__ __forceinline__ float bf2f(unsigned short u){ return __uint_as_float(((unsigned)u) << 16); }
__device__ __forceinline__ unsigned short f2bf(float f){
  unsigned v = __float_as_uint(f);
  return (unsigned short)((v + 0x7FFFu + ((v >> 16) & 1u)) >> 16);
}

// ================= conv1: 2->128 VALU, output pixel-major bf16 =================
__global__ __launch_bounds__(256) void conv1_kernel(
    const float* __restrict__ F, const float* __restrict__ W1, const float* __restrict__ b1,
    unsigned short* __restrict__ y1)
{
  __shared__ float xp[2*484];
  const int tid = threadIdx.x, b = blockIdx.x;
  for (int i = tid; i < 968; i += 256) xp[i] = 0.f;
  __syncthreads();
  for (int i = tid; i < 800; i += 256){
    int ci = i / 400, p = i - ci*400;
    xp[ci*484 + (p/20 + 1)*22 + (p%20) + 1] = F[((size_t)b*2 + ci)*400 + p];
  }
  __syncthreads();
  const int p0 = tid;
  const int p1 = tid + 256;
  const bool v1 = p1 < 400;
  float x0[18], x1[18];
  {
    int h = p0/20, w = p0 - (p0/20)*20;
#pragma unroll
    for (int ci = 0; ci < 2; ++ci)
#pragma unroll
      for (int dh = 0; dh < 3; ++dh)
#pragma unroll
        for (int dw = 0; dw < 3; ++dw)
          x0[ci*9 + dh*3 + dw] = xp[ci*484 + (h+dh)*22 + (w+dw)];
  }
  {
    int pc = v1 ? p1 : 0;
    int h = pc/20, w = pc - (pc/20)*20;
#pragma unroll
    for (int ci = 0; ci < 2; ++ci)
#pragma unroll
      for (int dh = 0; dh < 3; ++dh)
#pragma unroll
        for (int dw = 0; dw < 3; ++dw)
          x1[ci*9 + dh*3 + dw] = xp[ci*484 + (h+dh)*22 + (w+dw)];
  }
  for (int cg = 0; cg < 16; ++cg){
    float a0[8], a1[8];
#pragma unroll
    for (int co = 0; co < 8; ++co){ float bb = b1[cg*8+co]; a0[co] = bb; a1[co] = bb; }
#pragma unroll
    for (int co = 0; co < 8; ++co){
      const float* wq = W1 + (size_t)(cg*8 + co)*18;
#pragma unroll
      for (int k = 0; k < 18; ++k){
        float wv = wq[k];
        a0[co] = fmaf(x0[k], wv, a0[co]);
        a1[co] = fmaf(x1[k], wv, a1[co]);
      }
    }
    union { unsigned short u[8]; uint4 v; } pk;
#pragma unroll
    for (int co = 0; co < 8; ++co) pk.u[co] = f2bf(a0[co]);
    *(uint4*)(y1 + ((size_t)b*400 + p0)*128 + cg*8) = pk.v;
    if (v1){
#pragma unroll
      for (int co = 0; co < 8; ++co) pk.u[co] = f2bf(a1[co]);
      *(uint4*)(y1 + ((size_t)b*400 + p1)*128 + cg*8) = pk.v;
    }
  }
}

// ============ stats over pixel-major [B][400][128] bf16 (layer 1) ============
__global__ __launch_bounds__(256) void stats128_kernel(const unsigned short* __restrict__ y,
                                                       float* __restrict__ stats)
{
  const int tid = threadIdx.x;
  const int co = tid & 127, half = tid >> 7;
  const size_t base = (size_t)blockIdx.x * 400;
  float s = 0.f, q = 0.f;
  for (int i = 0; i < 200; ++i){
    float v = bf2f(y[(base + half*200 + i)*128 + co]);
    s += v; q = fmaf(v, v, q);
  }
  __shared__ float red[512];
  red[tid] = s; red[256 + tid] = q;
  __syncthreads();
  if (tid < 128){
    atomicAdd(&stats[co],       red[tid] + red[tid+128]);
    atomicAdd(&stats[128 + co], red[256+tid] + red[256+tid+128]);
  }
}

// ---------- fold stats -> per-channel scale/shift ----------
__global__ void bn_fin(const float* __restrict__ stats, const float* __restrict__ g,
                       const float* __restrict__ be, float* __restrict__ ss,
                       int C, float invN)
{
  int c = threadIdx.x;
  if (c < C){
    float mean = stats[c] * invN;
    float var  = stats[C + c] * invN - mean * mean;
    float sc   = g[c] * rsqrtf(var + 1e-5f);
    ss[c]      = sc;
    ss[C + c]  = be[c] - mean * sc;
  }
}

// ---------- weight pack into MFMA A-fragment order ----------
// Wpk[((ct*KC + kcg)*64 + lane)*8 + j] = W[co=ct*16+(lane&15)][ci][dh][dw],
// kg = kcg*32 + (lane>>4)*8 + j ; dhw = kg>>cin_shift ; ci = kg & (CIN-1)
__global__ void packw_kernel(const float* __restrict__ W, unsigned short* __restrict__ Wpk,
                             int KC, int cin_shift, int total)
{
  int idx = blockIdx.x*256 + threadIdx.x;
  if (idx >= total) return;
  int lane = idx & 63, t2 = idx >> 6;
  int kcg = t2 % KC, ct = t2 / KC;
  int co  = ct*16 + (lane & 15);
  int kg0 = kcg*32 + (lane >> 4)*8;
  int CIN = 1 << cin_shift;
#pragma unroll
  for (int j = 0; j < 8; ++j){
    int kg  = kg0 + j;
    int dhw = kg >> cin_shift;
    int ci  = kg & (CIN-1);
    Wpk[(size_t)idx*8 + j] = f2bf(W[((size_t)co*CIN + ci)*9 + dhw]);
  }
}

// ================= MFMA implicit-GEMM conv 3x3 SAME =================
// input  xin : [B][400][CIN] bf16 (pre-BN), BN+ReLU fused via ss_in
// output yout: [B][400][COUT] bf16 (pre-BN) + fused stats
template<int CIN, int COUT>
__global__ __launch_bounds__(256, 2) void conv_mfma(
    const unsigned short* __restrict__ xin, const float* __restrict__ ss_in,
    const unsigned short* __restrict__ Wpk, const float* __restrict__ bconv,
    unsigned short* __restrict__ yout, float* __restrict__ stats)
{
  constexpr int KC = (9*CIN)/32;
  constexpr int CT = COUT/16;
  __shared__ unsigned short xs[484*64];   // padded 22x22 x 64ci tile, 61952 B
  const int tid = threadIdx.x, b = blockIdx.x;
  const int wid = tid >> 6, lane = tid & 63, lq = lane >> 4, lr = lane & 15;

  // zero LDS (borders stay zero)
  uint4 z4 = {0,0,0,0};
  for (int i = tid; i < 484*8; i += 256) *(uint4*)&xs[(size_t)i*8] = z4;

  // per-slot pixel geometry (wave w owns pixel-tiles w, w+4, ...)
  int pp0[7]; bool act[7];
#pragma unroll
  for (int s = 0; s < 7; ++s){
    int pt = wid + s*4;
    act[s] = (pt < 25);
    int p  = (pt < 25 ? pt : 24)*16 + lr;
    int h  = p/20, w = p - (p/20)*20;
    pp0[s] = h*22 + w;
  }
  f32x4 zero4 = {0.f,0.f,0.f,0.f};
  f32x4 acc[CT][7];
#pragma unroll
  for (int ct = 0; ct < CT; ++ct)
#pragma unroll
    for (int s = 0; s < 7; ++s) acc[ct][s] = zero4;

  for (int cc = 0; cc < CIN; cc += 64){
    __syncthreads();
    // ---- stage: coalesced read + BN+ReLU + swizzled ds_write_b128 ----
    for (int i = tid; i < 3200; i += 256){
      int p = i >> 3, g = i & 7;
      int c = cc + g*8;
      ushort8 raw = *(const ushort8*)(xin + ((size_t)b*400 + p)*CIN + c);
      union { unsigned short u[8]; uint4 v; } pk;
#pragma unroll
      for (int j = 0; j < 8; ++j){
        float f = fmaf(bf2f(raw[j]), ss_in[c+j], ss_in[CIN + c + j]);
        pk.u[j] = f2bf(fmaxf(f, 0.f));
      }
      int pidx = (p/20 + 1)*22 + (p - (p/20)*20) + 1;
      *(uint4*)&xs[(size_t)(pidx*8 + (g ^ (pidx & 7)))*8] = pk.v;
    }
    __syncthreads();
    // ---- compute ----
#pragma unroll 1
    for (int dh = 0; dh < 3; ++dh){
#pragma unroll
      for (int dw = 0; dw < 3; ++dw){
        int dhw = dh*3 + dw;
        int doff = dh*22 + dw;
        bf16x8 af[2][CT];
#pragma unroll
        for (int sub = 0; sub < 2; ++sub){
          int kcg = dhw*(CIN/32) + (cc >> 5) + sub;
#pragma unroll
          for (int ct = 0; ct < CT; ++ct)
            af[sub][ct] = *(const bf16x8*)(Wpk + (((size_t)(ct*KC + kcg)*64 + lane) << 3));
        }
#pragma unroll
        for (int sub = 0; sub < 2; ++sub){
#pragma unroll
          for (int s = 0; s < 7; ++s){
            if (!act[s]) continue;           // wave-uniform
            int pidx = pp0[s] + doff;
            int gg = (sub*4 + lq) ^ (pidx & 7);
            bf16x8 bfr = *(const bf16x8*)&xs[(size_t)(pidx*8 + gg)*8];
#pragma unroll
            for (int ct = 0; ct < CT; ++ct)
              acc[ct][s] = __builtin_amdgcn_mfma_f32_16x16x32_bf16(af[sub][ct], bfr, acc[ct][s], 0, 0, 0);
          }
        }
      }
    }
  }

  // ---- epilogue: bias, bf16 store pixel-major, fused stats ----
  float sm[CT][4], sq2[CT][4];
#pragma unroll
  for (int ct = 0; ct < CT; ++ct)
#pragma unroll
    for (int r = 0; r < 4; ++r){ sm[ct][r] = 0.f; sq2[ct][r] = 0.f; }

#pragma unroll
  for (int s = 0; s < 7; ++s){
    if (!act[s]) continue;
    int px = (wid + s*4)*16 + lr;
#pragma unroll
    for (int ct = 0; ct < CT; ++ct){
      f32x4 bias = *(const f32x4*)(bconv + ct*16 + lq*4);
      f32x4 y = acc[ct][s] + bias;
      union { unsigned short u[4]; ushort2 h[2]; unsigned long long ll; } pk;
#pragma unroll
      for (int r = 0; r < 4; ++r){
        pk.u[r] = f2bf(y[r]);
        sm[ct][r]  += y[r];
        sq2[ct][r] = fmaf(y[r], y[r], sq2[ct][r]);
      }
      *(unsigned long long*)(yout + ((size_t)b*400 + px)*COUT + ct*16 + lq*4) = pk.ll;
    }
  }
#pragma unroll
  for (int ct = 0; ct < CT; ++ct)
#pragma unroll
    for (int r = 0; r < 4; ++r){
      float v = sm[ct][r], w = sq2[ct][r];
#pragma unroll
      for (int m = 1; m < 16; m <<= 1){ v += __shfl_xor(v, m); w += __shfl_xor(w, m); }
      if (lr == 0){
        atomicAdd(&stats[ct*16 + lq*4 + r], v);
        atomicAdd(&stats[COUT + ct*16 + lq*4 + r], w);
      }
    }
}

// ---------- BN+ReLU on y4 (pixel-major, 32 ch) -> a4 bf16 ----------
__global__ __launch_bounds__(256) void act4_kernel(const unsigned short* __restrict__ y4,
                                                   const float* __restrict__ ss,
                                                   unsigned short* __restrict__ a4)
{
  int i = blockIdx.x*256 + threadIdx.x;
  if (i >= 819200) return;
  int c0 = (i & 3)*8;
  ushort8 raw = *(const ushort8*)(y4 + (size_t)i*8);
  union { unsigned short u[8]; uint4 v; } pk;
#pragma unroll
  for (int j = 0; j < 8; ++j){
    float f = fmaf(bf2f(raw[j]), ss[c0+j], ss[32 + c0 + j]);
    pk.u[j] = f2bf(fmaxf(f, 0.f));
  }
  *(uint4*)(a4 + (size_t)i*8) = pk.v;
}

// ---------- permute Wo[j][c*400+p] -> WoPM[(p*32+c)*200+j] ----------
__global__ __launch_bounds__(256) void woprep_kernel(const float* __restrict__ Wo,
                                                     float* __restrict__ WoPM)
{
  __shared__ float t[200*41];
  const int tid = threadIdx.x;
  const int c = blockIdx.x, p0 = blockIdx.y*40;
  for (int i = tid; i < 8000; i += 256){
    int j = i/40, pp = i - j*40;
    t[j*41 + pp] = Wo[(size_t)j*12800 + c*400 + p0 + pp];
  }
  __syncthreads();
  for (int i = tid; i < 8000; i += 256){
    int pp = i/200, j = i - pp*200;
    WoPM[((size_t)(p0+pp)*32 + c)*200 + j] = t[j*41 + pp];
  }
}

// ---------- init linear out with bias ----------
__global__ void lin_init(const float* __restrict__ bo, float* __restrict__ lin, int total)
{
  int i = blockIdx.x*256 + threadIdx.x;
  if (i < total) lin[i] = bo[i % 200];
}

// ---------- linear: lin[b][j] += sum_k a4[b][k] * WoPM[k][j], K split 8-way ----------
__global__ __launch_bounds__(256) void linear_kernel(const unsigned short* __restrict__ a4,
                                                     const float* __restrict__ WoPM,
                                                     float* __restrict__ lin)
{
  __shared__ float At[64][68];
  __shared__ float Bt[64][68];
  const int tid = threadIdx.x;
  const int b0 = blockIdx.x * 64;
  const int j0 = blockIdx.y * 64;
  const int k0 = blockIdx.z * 1600;
  const int rowg = tid & 15;
  const int colg = tid >> 4;
  float acc[4][4];
#pragma unroll
  for (int r = 0; r < 4; ++r)
#pragma unroll
    for (int c = 0; c < 4; ++c) acc[r][c] = 0.f;

  for (int kt = k0; kt < k0 + 1600; kt += 64){
    __syncthreads();
    for (int i = tid; i < 4096; i += 256){
      int r = i >> 6, kk = i & 63;
      At[kk][r] = bf2f(a4[(size_t)(b0 + r)*12800 + kt + kk]);
    }
    for (int i = tid; i < 4096; i += 256){
      int c = i & 63, kk = i >> 6;
      int j = j0 + c;
      Bt[kk][c] = (j < 200) ? WoPM[(size_t)(kt + kk)*200 + j] : 0.f;
    }
    __syncthreads();
#pragma unroll 4
    for (int kk = 0; kk < 64; ++kk){
      float4 av = *reinterpret_cast<const float4*>(&At[kk][rowg*4]);
      float4 bv = *reinterpret_cast<const float4*>(&Bt[kk][colg*4]);
      float a[4]  = {av.x, av.y, av.z, av.w};
      float bb[4] = {bv.x, bv.y, bv.z, bv.w};
#pragma unroll
      for (int r = 0; r < 4; ++r)
#pragma unroll
        for (int c = 0; c < 4; ++c) acc[r][c] = fmaf(a[r], bb[c], acc[r][c]);
    }
  }
#pragma unroll
  for (int r = 0; r < 4; ++r){
    int bb = b0 + rowg*4 + r;
#pragma unroll
    for (int c = 0; c < 4; ++c){
      int j = j0 + colg*4 + c;
      if (j < 200) atomicAdd(&lin[(size_t)bb*200 + j], acc[r][c]);
    }
  }
}

// ---------- phase + einsum + norm ----------
__global__ __launch_bounds__(256) void phase_kernel(const float* __restrict__ lin,
                                                    const float* __restrict__ Gr,
                                                    const float* __restrict__ Gi,
                                                    const float* __restrict__ hrr,
                                                    const float* __restrict__ hri,
                                                    float* __restrict__ accum)
{
  const int b = blockIdx.x;
  const int tid = threadIdx.x;
  __shared__ float u[100];
  __shared__ float pp[100];
  __shared__ float redbuf[4];
  if (tid < 100){
    float t1 = lin[b*200 + tid];
    float t2 = lin[b*200 + 100 + tid];
    float c = cosf(t1);
    float s = sinf(t2);
    float hr = hrr[b*100 + tid];
    float hi = hri[b*100 + tid];
    u[tid]  = c*hr - s*hi;
    pp[tid] = c*hi + s*hr;
  }
  __syncthreads();
  const int m = tid;
  const float4* grow  = (const float4*)(Gr + ((size_t)b*256 + m)*100);
  const float4* girow = (const float4*)(Gi + ((size_t)b*256 + m)*100);
  float tr = 0.f, ti = 0.f;
#pragma unroll
  for (int i = 0; i < 25; ++i){
    float4 g  = grow[i];
    float4 gg = girow[i];
    float4 uu = *(const float4*)&u[i*4];
    float4 qq = *(const float4*)&pp[i*4];
    tr += g.x*uu.x - gg.x*qq.x;  ti += g.x*qq.x + gg.x*uu.x;
    tr += g.y*uu.y - gg.y*qq.y;  ti += g.y*qq.y + gg.y*uu.y;
    tr += g.z*uu.z - gg.z*qq.z;  ti += g.z*qq.z + gg.z*uu.z;
    tr += g.w*uu.w - gg.w*qq.w;  ti += g.w*qq.w + gg.w*uu.w;
  }
  float ns = tr*tr + ti*ti;
#pragma unroll
  for (int off = 32; off; off >>= 1) ns += __shfl_down(ns, off);
  if ((tid & 63) == 0) redbuf[tid >> 6] = ns;
  __syncthreads();
  if (tid == 0) atomicAdd(accum, redbuf[0] + redbuf[1] + redbuf[2] + redbuf[3]);
}

__global__ void finalize_kernel(const float* __restrict__ accum, float* __restrict__ out)
{
  out[0] = -accum[0] * (1.0f / 512.0f);
}

extern "C" void kernel_launch(void* const* d_in, const int* in_sizes, int n_in,
                              void* d_out, int out_size, void* d_ws, size_t ws_size,
                              hipStream_t stream)
{
  const float* F   = (const float*)d_in[0];
  const float* Gr  = (const float*)d_in[1];
  const float* Gi  = (const float*)d_in[2];
  const float* hrr = (const float*)d_in[3];
  const float* hri = (const float*)d_in[4];
  const float* W1  = (const float*)d_in[5];
  const float* b1  = (const float*)d_in[6];
  const float* g1  = (const float*)d_in[7];
  const float* be1 = (const float*)d_in[8];
  const float* W2  = (const float*)d_in[9];
  const float* b2  = (const float*)d_in[10];
  const float* g2  = (const float*)d_in[11];
  const float* be2 = (const float*)d_in[12];
  const float* W3  = (const float*)d_in[13];
  const float* b3  = (const float*)d_in[14];
  const float* g3  = (const float*)d_in[15];
  const float* be3 = (const float*)d_in[16];
  const float* W4  = (const float*)d_in[17];
  const float* b4  = (const float*)d_in[18];
  const float* g4  = (const float*)d_in[19];
  const float* be4 = (const float*)d_in[20];
  const float* Wo  = (const float*)d_in[21];
  const float* bo  = (const float*)d_in[22];

  char* ws = (char*)d_ws;
  // region A: 52,428,800 B  (y1 ; then y3 ; then a4)
  // region B: 26,214,400 B  (y2 ; then y4 + WoPM at +13,107,200)
  unsigned short* y1  = (unsigned short*)(ws);
  unsigned short* y2  = (unsigned short*)(ws + 52428800);
  unsigned short* y3  = (unsigned short*)(ws);
  unsigned short* y4  = (unsigned short*)(ws + 52428800);
  unsigned short* a4  = (unsigned short*)(ws);
  float*          WoPM= (float*)(ws + 52428800 + 13107200);
  float* lin   = (float*)(ws + 78643200);                 // 409,600 B
  float* stats = (float*)(ws + 79052800);                 // 4096 B
  float* ssb   = (float*)(ws + 79056896);                 // 4096 B
  float* accum = (float*)(ws + 79060992);                 // 16 B
  unsigned short* Wpk2 = (unsigned short*)(ws + 79061008); // 147,456 B
  unsigned short* Wpk3 = (unsigned short*)(ws + 79208464); //  73,728 B
  unsigned short* Wpk4 = (unsigned short*)(ws + 79282192); //  36,864 B

  hipMemsetAsync(ws + 79052800, 0, 8208, stream);   // stats + ss + accum

  const float invN = 1.0f / 204800.0f;

  // weight packs (independent of data flow; cheap)
  packw_kernel<<<36, 256, 0, stream>>>(W2, Wpk2, 36, 7, 9216);
  packw_kernel<<<18, 256, 0, stream>>>(W3, Wpk3, 18, 6, 4608);
  packw_kernel<<< 9, 256, 0, stream>>>(W4, Wpk4, 18, 6, 2304);

  // conv1 + stats1
  conv1_kernel<<<512, 256, 0, stream>>>(F, W1, b1, y1);
  stats128_kernel<<<512, 256, 0, stream>>>(y1, stats);
  bn_fin<<<1, 128, 0, stream>>>(stats, g1, be1, ssb, 128, invN);

  // conv2: 128 -> 64
  conv_mfma<128, 64><<<512, 256, 0, stream>>>(y1, ssb, Wpk2, b2, y2, stats + 256);
  bn_fin<<<1, 64, 0, stream>>>(stats + 256, g2, be2, ssb + 256, 64, invN);

  // conv3: 64 -> 64
  conv_mfma<64, 64><<<512, 256, 0, stream>>>(y2, ssb + 256, Wpk3, b3, y3, stats + 512);
  bn_fin<<<1, 64, 0, stream>>>(stats + 512, g3, be3, ssb + 512, 64, invN);

  // conv4: 64 -> 32
  conv_mfma<64, 32><<<512, 256, 0, stream>>>(y3, ssb + 512, Wpk4, b4, y4, stats + 768);
  bn_fin<<<1, 32, 0, stream>>>(stats + 768, g4, be4, ssb + 768, 32, invN);

  // Wo permute (region B tail is free after conv3; disjoint from y4)
  woprep_kernel<<<dim3(32, 10), 256, 0, stream>>>(Wo, WoPM);

  // act4 -> a4 (region A; y3 dead)
  act4_kernel<<<3200, 256, 0, stream>>>(y4, ssb + 768, a4);

  // linear 12800 -> 200
  lin_init<<<400, 256, 0, stream>>>(bo, lin, 102400);
  linear_kernel<<<dim3(8, 4, 8), 256, 0, stream>>>(a4, WoPM, lin);

  // phase + norm
  phase_kernel<<<512, 256, 0, stream>>>(lin, Gr, Gi, hrr, hri, accum);
  finalize_kernel<<<1, 1, 0, stream>>>(accum, (float*)d_out);
}

// Round 3
// 664.141 us; speedup vs baseline: 8.2732x; 1.6008x over previous
//
#include <hip/hip_runtime.h>
#include <math.h>

typedef __bf16 bf16x8 __attribute__((ext_vector_type(8)));
typedef float f32x4 __attribute__((ext_vector_type(4)));
typedef unsigned short ushort8 __attribute__((ext_vector_type(8)));

__device__ __forceinline__ float bf2f(unsigned short u){ return __uint_as_float(((unsigned)u) << 16); }
__device__ __forceinline__ unsigned short f2bf(float f){
  unsigned v = __float_as_uint(f);
  return (unsigned short)((v + 0x7FFFu + ((v >> 16) & 1u)) >> 16);
}

// ================= conv1: 2->128 VALU, output pixel-major bf16 =================
__global__ __launch_bounds__(256) void conv1_kernel(
    const float* __restrict__ F, const float* __restrict__ W1, const float* __restrict__ b1,
    unsigned short* __restrict__ y1)
{
  __shared__ float xp[2*484];
  const int tid = threadIdx.x, b = blockIdx.x;
  for (int i = tid; i < 968; i += 256) xp[i] = 0.f;
  __syncthreads();
  for (int i = tid; i < 800; i += 256){
    int ci = i / 400, p = i - ci*400;
    xp[ci*484 + (p/20 + 1)*22 + (p%20) + 1] = F[((size_t)b*2 + ci)*400 + p];
  }
  __syncthreads();
  const int p0 = tid;
  const int p1 = tid + 256;
  const bool v1 = p1 < 400;
  float x0[18], x1[18];
  {
    int h = p0/20, w = p0 - (p0/20)*20;
#pragma unroll
    for (int ci = 0; ci < 2; ++ci)
#pragma unroll
      for (int dh = 0; dh < 3; ++dh)
#pragma unroll
        for (int dw = 0; dw < 3; ++dw)
          x0[ci*9 + dh*3 + dw] = xp[ci*484 + (h+dh)*22 + (w+dw)];
  }
  {
    int pc = v1 ? p1 : 0;
    int h = pc/20, w = pc - (pc/20)*20;
#pragma unroll
    for (int ci = 0; ci < 2; ++ci)
#pragma unroll
      for (int dh = 0; dh < 3; ++dh)
#pragma unroll
        for (int dw = 0; dw < 3; ++dw)
          x1[ci*9 + dh*3 + dw] = xp[ci*484 + (h+dh)*22 + (w+dw)];
  }
  for (int cg = 0; cg < 16; ++cg){
    float a0[8], a1[8];
#pragma unroll
    for (int co = 0; co < 8; ++co){ float bb = b1[cg*8+co]; a0[co] = bb; a1[co] = bb; }
#pragma unroll
    for (int co = 0; co < 8; ++co){
      const float* wq = W1 + (size_t)(cg*8 + co)*18;
#pragma unroll
      for (int k = 0; k < 18; ++k){
        float wv = wq[k];
        a0[co] = fmaf(x0[k], wv, a0[co]);
        a1[co] = fmaf(x1[k], wv, a1[co]);
      }
    }
    union { unsigned short u[8]; uint4 v; } pk;
#pragma unroll
    for (int co = 0; co < 8; ++co) pk.u[co] = f2bf(a0[co]);
    *(uint4*)(y1 + ((size_t)b*400 + p0)*128 + cg*8) = pk.v;
    if (v1){
#pragma unroll
      for (int co = 0; co < 8; ++co) pk.u[co] = f2bf(a1[co]);
      *(uint4*)(y1 + ((size_t)b*400 + p1)*128 + cg*8) = pk.v;
    }
  }
}

// ============ stats over pixel-major [B][400][128] bf16 (layer 1), vectorized ============
__global__ __launch_bounds__(256) void stats128_kernel(const unsigned short* __restrict__ y,
                                                       float* __restrict__ stats)
{
  const int tid = threadIdx.x;
  const int o = tid & 15, pr = tid >> 4;   // octet, pixel-stride
  float s[8], q[8];
#pragma unroll
  for (int j = 0; j < 8; ++j){ s[j] = 0.f; q[j] = 0.f; }
  const unsigned short* base = y + (size_t)blockIdx.x * 400 * 128;
  for (int p = pr; p < 400; p += 16){
    ushort8 raw = *(const ushort8*)(base + (size_t)p*128 + o*8);
#pragma unroll
    for (int j = 0; j < 8; ++j){ float v = bf2f(raw[j]); s[j] += v; q[j] = fmaf(v, v, q[j]); }
  }
#pragma unroll
  for (int j = 0; j < 8; ++j){
    s[j] += __shfl_xor(s[j], 16); s[j] += __shfl_xor(s[j], 32);
    q[j] += __shfl_xor(q[j], 16); q[j] += __shfl_xor(q[j], 32);
  }
  __shared__ float red[2][4][16][8];
  const int w = tid >> 6, l = tid & 63;
  if ((l >> 4) == 0){
#pragma unroll
    for (int j = 0; j < 8; ++j){ red[0][w][l][j] = s[j]; red[1][w][l][j] = q[j]; }
  }
  __syncthreads();
  {
    int st = tid >> 7, co = tid & 127, oo = co >> 3, j = co & 7;
    float v = red[st][0][oo][j] + red[st][1][oo][j] + red[st][2][oo][j] + red[st][3][oo][j];
    atomicAdd(&stats[st*128 + co], v);
  }
}

// ---------- fold stats -> per-channel scale/shift ----------
__global__ void bn_fin(const float* __restrict__ stats, const float* __restrict__ g,
                       const float* __restrict__ be, float* __restrict__ ss,
                       int C, float invN)
{
  int c = threadIdx.x;
  if (c < C){
    float mean = stats[c] * invN;
    float var  = stats[C + c] * invN - mean * mean;
    float sc   = g[c] * rsqrtf(var + 1e-5f);
    ss[c]      = sc;
    ss[C + c]  = be[c] - mean * sc;
  }
}

// ---------- weight pack into MFMA A-fragment order ----------
__global__ void packw_kernel(const float* __restrict__ W, unsigned short* __restrict__ Wpk,
                             int KC, int cin_shift, int total)
{
  int idx = blockIdx.x*256 + threadIdx.x;
  if (idx >= total) return;
  int lane = idx & 63, t2 = idx >> 6;
  int kcg = t2 % KC, ct = t2 / KC;
  int co  = ct*16 + (lane & 15);
  int kg0 = kcg*32 + (lane >> 4)*8;
  int CIN = 1 << cin_shift;
#pragma unroll
  for (int j = 0; j < 8; ++j){
    int kg  = kg0 + j;
    int dhw = kg >> cin_shift;
    int ci  = kg & (CIN-1);
    Wpk[(size_t)idx*8 + j] = f2bf(W[((size_t)co*CIN + ci)*9 + dhw]);
  }
}

// ================= MFMA implicit-GEMM conv 3x3 SAME (v2: 64-pixel blocks) =================
// xin [B][400][CIN] bf16 pre-BN; BN+ReLU via ss_in; yout [B][400][COUT] bf16 + stats.
template<int CIN, int COUT>
__global__ __launch_bounds__(256, 3) void conv_mfma(
    const unsigned short* __restrict__ xin, const float* __restrict__ ss_in,
    const unsigned short* __restrict__ Wpk, const float* __restrict__ bconv,
    unsigned short* __restrict__ yout, float* __restrict__ stats)
{
  constexpr int NG   = CIN/8;        // ci-octets per pixel
  constexpr int LOGNG= (CIN==128) ? 4 : 3;
  constexpr int KC   = (9*CIN)/32;
  constexpr int NSUB = CIN/32;
  constexpr int CT_W = (COUT==64) ? 2 : 1;
  __shared__ unsigned short xs[120*CIN];
  __shared__ float sred[2*COUT];

  const int tid = threadIdx.x;
  const int b = blockIdx.x, t = blockIdx.y;
  const int q0 = t*64;
  const int rb = q0/20 - 1;           // first staged image row
  const int wid = tid >> 6, lane = tid & 63, lq = lane >> 4, lr = lane & 15;

  for (int i = tid; i < 2*COUT; i += 256) sred[i] = 0.f;

  // ---- stage 120 pixels (6 rows), linear layout + octet XOR swizzle ----
  {
    const int g = tid & (NG-1);
    const int c = g*8;
    f32x4 s0 = *(const f32x4*)(ss_in + c);
    f32x4 s1 = *(const f32x4*)(ss_in + c + 4);
    f32x4 h0 = *(const f32x4*)(ss_in + CIN + c);
    f32x4 h1 = *(const f32x4*)(ss_in + CIN + c + 4);
    for (int i = tid; i < 120*NG; i += 256){
      int L  = i >> LOGNG;
      int ps = rb*20 + L;
      union { unsigned short u[8]; uint4 v; } pk;
      if (ps >= 0 && ps < 400){
        ushort8 raw = *(const ushort8*)(xin + ((size_t)b*400 + ps)*CIN + c);
        pk.u[0] = f2bf(fmaxf(fmaf(bf2f(raw[0]), s0[0], h0[0]), 0.f));
        pk.u[1] = f2bf(fmaxf(fmaf(bf2f(raw[1]), s0[1], h0[1]), 0.f));
        pk.u[2] = f2bf(fmaxf(fmaf(bf2f(raw[2]), s0[2], h0[2]), 0.f));
        pk.u[3] = f2bf(fmaxf(fmaf(bf2f(raw[3]), s0[3], h0[3]), 0.f));
        pk.u[4] = f2bf(fmaxf(fmaf(bf2f(raw[4]), s1[0], h1[0]), 0.f));
        pk.u[5] = f2bf(fmaxf(fmaf(bf2f(raw[5]), s1[1], h1[1]), 0.f));
        pk.u[6] = f2bf(fmaxf(fmaf(bf2f(raw[6]), s1[2], h1[2]), 0.f));
        pk.u[7] = f2bf(fmaxf(fmaf(bf2f(raw[7]), s1[3], h1[3]), 0.f));
      } else {
        pk.v.x = 0u; pk.v.y = 0u; pk.v.z = 0u; pk.v.w = 0u;
      }
      *(uint4*)&xs[(size_t)((L << LOGNG) + (g ^ (L & 7)))*8] = pk.v;
    }
  }
  __syncthreads();

  // ---- wave tiling: (ct-group, pixel-tile pair) ----
  const int ct0 = (wid & 1) * CT_W;
  const int pt0 = (wid >> 1) * 2;
  int Lq[2], px[2]; bool mL[2], mR[2];
#pragma unroll
  for (int k2 = 0; k2 < 2; ++k2){
    int q = q0 + (pt0 + k2)*16 + lr;
    px[k2] = q;
    int w  = q % 20;
    mL[k2] = (w == 0); mR[k2] = (w == 19);
    Lq[k2] = q - 20*rb;
  }
  f32x4 acc[CT_W][2];
#pragma unroll
  for (int c2 = 0; c2 < CT_W; ++c2)
#pragma unroll
    for (int k2 = 0; k2 < 2; ++k2){ acc[c2][k2][0]=0.f; acc[c2][k2][1]=0.f; acc[c2][k2][2]=0.f; acc[c2][k2][3]=0.f; }

  // ---- K loop: 9 taps x NSUB 32-chunks, no barriers, no guards ----
#pragma unroll 3
  for (int dhw = 0; dhw < 9; ++dhw){
    const int dr = dhw/3 - 1, dc = dhw%3 - 1;
    const int doff = dr*20 + dc;
#pragma unroll
    for (int sub = 0; sub < NSUB; ++sub){
      bf16x8 af[CT_W];
#pragma unroll
      for (int c2 = 0; c2 < CT_W; ++c2)
        af[c2] = *(const bf16x8*)(Wpk + (((size_t)((ct0+c2)*KC + dhw*NSUB + sub)*64 + lane) << 3));
      bf16x8 bf[2];
#pragma unroll
      for (int k2 = 0; k2 < 2; ++k2){
        int Lt = Lq[k2] + doff;
        Lt = Lt < 0 ? 0 : (Lt > 119 ? 119 : Lt);
        int addr = (Lt << LOGNG) + ((sub*4 + lq) ^ (Lt & 7));
        union { uint4 v; bf16x8 h; } u;
        u.h = *(const bf16x8*)&xs[(size_t)addr*8];
        if (dc != 0){
          bool dead = (dc < 0) ? mL[k2] : mR[k2];
          unsigned keep = dead ? 0u : 0xFFFFFFFFu;
          u.v.x &= keep; u.v.y &= keep; u.v.z &= keep; u.v.w &= keep;
        }
        bf[k2] = u.h;
      }
#pragma unroll
      for (int c2 = 0; c2 < CT_W; ++c2)
#pragma unroll
        for (int k2 = 0; k2 < 2; ++k2)
          acc[c2][k2] = __builtin_amdgcn_mfma_f32_16x16x32_bf16(af[c2], bf[k2], acc[c2][k2], 0, 0, 0);
    }
  }

  // ---- epilogue: bias, store, stats (shfl -> LDS -> 1 global atomic/ch) ----
  float smv[CT_W][4], sqv[CT_W][4];
#pragma unroll
  for (int c2 = 0; c2 < CT_W; ++c2)
#pragma unroll
    for (int r = 0; r < 4; ++r){ smv[c2][r] = 0.f; sqv[c2][r] = 0.f; }

#pragma unroll
  for (int c2 = 0; c2 < CT_W; ++c2){
    f32x4 bias = *(const f32x4*)(bconv + (ct0+c2)*16 + lq*4);
#pragma unroll
    for (int k2 = 0; k2 < 2; ++k2){
      bool ok = px[k2] < 400;
      f32x4 y = acc[c2][k2] + bias;
      union { unsigned short u[4]; unsigned long long ll; } pk;
#pragma unroll
      for (int r = 0; r < 4; ++r){
        float yv = ok ? y[r] : 0.f;
        pk.u[r] = f2bf(y[r]);
        smv[c2][r] += yv;
        sqv[c2][r] = fmaf(yv, yv, sqv[c2][r]);
      }
      if (ok)
        *(unsigned long long*)(yout + ((size_t)b*400 + px[k2])*COUT + (ct0+c2)*16 + lq*4) = pk.ll;
    }
  }
#pragma unroll
  for (int c2 = 0; c2 < CT_W; ++c2)
#pragma unroll
    for (int r = 0; r < 4; ++r){
      float v = smv[c2][r], w2 = sqv[c2][r];
#pragma unroll
      for (int m = 1; m < 16; m <<= 1){ v += __shfl_xor(v, m); w2 += __shfl_xor(w2, m); }
      if (lr == 0){
        int co = (ct0+c2)*16 + lq*4 + r;
        atomicAdd(&sred[co], v);
        atomicAdd(&sred[COUT + co], w2);
      }
    }
  __syncthreads();
  for (int i = tid; i < 2*COUT; i += 256)
    atomicAdd(&stats[i], sred[i]);
}

// ---------- BN+ReLU on y4 (pixel-major, 32 ch) -> a4 bf16 ----------
__global__ __launch_bounds__(256) void act4_kernel(const unsigned short* __restrict__ y4,
                                                   const float* __restrict__ ss,
                                                   unsigned short* __restrict__ a4)
{
  int i = blockIdx.x*256 + threadIdx.x;
  if (i >= 819200) return;
  int c0 = (i & 3)*8;
  ushort8 raw = *(const ushort8*)(y4 + (size_t)i*8);
  union { unsigned short u[8]; uint4 v; } pk;
#pragma unroll
  for (int j = 0; j < 8; ++j){
    float f = fmaf(bf2f(raw[j]), ss[c0+j], ss[32 + c0 + j]);
    pk.u[j] = f2bf(fmaxf(f, 0.f));
  }
  *(uint4*)(a4 + (size_t)i*8) = pk.v;
}

// ---------- permute Wo[j][c*400+p] -> WoPM[(p*32+c)*200+j] ----------
__global__ __launch_bounds__(256) void woprep_kernel(const float* __restrict__ Wo,
                                                     float* __restrict__ WoPM)
{
  __shared__ float t[200*41];
  const int tid = threadIdx.x;
  const int c = blockIdx.x, p0 = blockIdx.y*40;
  for (int i = tid; i < 8000; i += 256){
    int j = i/40, pp = i - j*40;
    t[j*41 + pp] = Wo[(size_t)j*12800 + c*400 + p0 + pp];
  }
  __syncthreads();
  for (int i = tid; i < 8000; i += 256){
    int pp = i/200, j = i - pp*200;
    WoPM[((size_t)(p0+pp)*32 + c)*200 + j] = t[j*41 + pp];
  }
}

// ---------- init linear out with bias ----------
__global__ void lin_init(const float* __restrict__ bo, float* __restrict__ lin, int total)
{
  int i = blockIdx.x*256 + threadIdx.x;
  if (i < total) lin[i] = bo[i % 200];
}

// ---------- linear: lin[b][j] += sum_k a4[b][k] * WoPM[k][j], K split 8-way ----------
__global__ __launch_bounds__(256) void linear_kernel(const unsigned short* __restrict__ a4,
                                                     const float* __restrict__ WoPM,
                                                     float* __restrict__ lin)
{
  __shared__ float At[64][68];
  __shared__ float Bt[64][68];
  const int tid = threadIdx.x;
  const int b0 = blockIdx.x * 64;
  const int j0 = blockIdx.y * 64;
  const int k0 = blockIdx.z * 1600;
  const int rowg = tid & 15;
  const int colg = tid >> 4;
  float acc[4][4];
#pragma unroll
  for (int r = 0; r < 4; ++r)
#pragma unroll
    for (int c = 0; c < 4; ++c) acc[r][c] = 0.f;

  for (int kt = k0; kt < k0 + 1600; kt += 64){
    __syncthreads();
    for (int i = tid; i < 4096; i += 256){
      int r = i >> 6, kk = i & 63;
      At[kk][r] = bf2f(a4[(size_t)(b0 + r)*12800 + kt + kk]);
    }
    for (int i = tid; i < 4096; i += 256){
      int c = i & 63, kk = i >> 6;
      int j = j0 + c;
      Bt[kk][c] = (j < 200) ? WoPM[(size_t)(kt + kk)*200 + j] : 0.f;
    }
    __syncthreads();
#pragma unroll 4
    for (int kk = 0; kk < 64; ++kk){
      float4 av = *reinterpret_cast<const float4*>(&At[kk][rowg*4]);
      float4 bv = *reinterpret_cast<const float4*>(&Bt[kk][colg*4]);
      float a[4]  = {av.x, av.y, av.z, av.w};
      float bb[4] = {bv.x, bv.y, bv.z, bv.w};
#pragma unroll
      for (int r = 0; r < 4; ++r)
#pragma unroll
        for (int c = 0; c < 4; ++c) acc[r][c] = fmaf(a[r], bb[c], acc[r][c]);
    }
  }
#pragma unroll
  for (int r = 0; r < 4; ++r){
    int bb = b0 + rowg*4 + r;
#pragma unroll
    for (int c = 0; c < 4; ++c){
      int j = j0 + colg*4 + c;
      if (j < 200) atomicAdd(&lin[(size_t)bb*200 + j], acc[r][c]);
    }
  }
}

// ---------- phase + einsum + norm ----------
__global__ __launch_bounds__(256) void phase_kernel(const float* __restrict__ lin,
                                                    const float* __restrict__ Gr,
                                                    const float* __restrict__ Gi,
                                                    const float* __restrict__ hrr,
                                                    const float* __restrict__ hri,
                                                    float* __restrict__ accum)
{
  const int b = blockIdx.x;
  const int tid = threadIdx.x;
  __shared__ float u[100];
  __shared__ float pp[100];
  __shared__ float redbuf[4];
  if (tid < 100){
    float t1 = lin[b*200 + tid];
    float t2 = lin[b*200 + 100 + tid];
    float c = cosf(t1);
    float s = sinf(t2);
    float hr = hrr[b*100 + tid];
    float hi = hri[b*100 + tid];
    u[tid]  = c*hr - s*hi;
    pp[tid] = c*hi + s*hr;
  }
  __syncthreads();
  const int m = tid;
  const float4* grow  = (const float4*)(Gr + ((size_t)b*256 + m)*100);
  const float4* girow = (const float4*)(Gi + ((size_t)b*256 + m)*100);
  float tr = 0.f, ti = 0.f;
#pragma unroll
  for (int i = 0; i < 25; ++i){
    float4 g  = grow[i];
    float4 gg = girow[i];
    float4 uu = *(const float4*)&u[i*4];
    float4 qq = *(const float4*)&pp[i*4];
    tr += g.x*uu.x - gg.x*qq.x;  ti += g.x*qq.x + gg.x*uu.x;
    tr += g.y*uu.y - gg.y*qq.y;  ti += g.y*qq.y + gg.y*uu.y;
    tr += g.z*uu.z - gg.z*qq.z;  ti += g.z*qq.z + gg.z*uu.z;
    tr += g.w*uu.w - gg.w*qq.w;  ti += g.w*qq.w + gg.w*uu.w;
  }
  float ns = tr*tr + ti*ti;
#pragma unroll
  for (int off = 32; off; off >>= 1) ns += __shfl_down(ns, off);
  if ((tid & 63) == 0) redbuf[tid >> 6] = ns;
  __syncthreads();
  if (tid == 0) atomicAdd(accum, redbuf[0] + redbuf[1] + redbuf[2] + redbuf[3]);
}

__global__ void finalize_kernel(const float* __restrict__ accum, float* __restrict__ out)
{
  out[0] = -accum[0] * (1.0f / 512.0f);
}

extern "C" void kernel_launch(void* const* d_in, const int* in_sizes, int n_in,
                              void* d_out, int out_size, void* d_ws, size_t ws_size,
                              hipStream_t stream)
{
  const float* F   = (const float*)d_in[0];
  const float* Gr  = (const float*)d_in[1];
  const float* Gi  = (const float*)d_in[2];
  const float* hrr = (const float*)d_in[3];
  const float* hri = (const float*)d_in[4];
  const float* W1  = (const float*)d_in[5];
  const float* b1  = (const float*)d_in[6];
  const float* g1  = (const float*)d_in[7];
  const float* be1 = (const float*)d_in[8];
  const float* W2  = (const float*)d_in[9];
  const float* b2  = (const float*)d_in[10];
  const float* g2  = (const float*)d_in[11];
  const float* be2 = (const float*)d_in[12];
  const float* W3  = (const float*)d_in[13];
  const float* b3  = (const float*)d_in[14];
  const float* g3  = (const float*)d_in[15];
  const float* be3 = (const float*)d_in[16];
  const float* W4  = (const float*)d_in[17];
  const float* b4  = (const float*)d_in[18];
  const float* g4  = (const float*)d_in[19];
  const float* be4 = (const float*)d_in[20];
  const float* Wo  = (const float*)d_in[21];
  const float* bo  = (const float*)d_in[22];

  char* ws = (char*)d_ws;
  unsigned short* y1  = (unsigned short*)(ws);
  unsigned short* y2  = (unsigned short*)(ws + 52428800);
  unsigned short* y3  = (unsigned short*)(ws);
  unsigned short* y4  = (unsigned short*)(ws + 52428800);
  unsigned short* a4  = (unsigned short*)(ws);
  float*          WoPM= (float*)(ws + 52428800 + 13107200);
  float* lin   = (float*)(ws + 78643200);
  float* stats = (float*)(ws + 79052800);
  float* ssb   = (float*)(ws + 79056896);
  float* accum = (float*)(ws + 79060992);
  unsigned short* Wpk2 = (unsigned short*)(ws + 79061008);
  unsigned short* Wpk3 = (unsigned short*)(ws + 79208464);
  unsigned short* Wpk4 = (unsigned short*)(ws + 79282192);

  hipMemsetAsync(ws + 79052800, 0, 8208, stream);

  const float invN = 1.0f / 204800.0f;

  packw_kernel<<<36, 256, 0, stream>>>(W2, Wpk2, 36, 7, 9216);
  packw_kernel<<<18, 256, 0, stream>>>(W3, Wpk3, 18, 6, 4608);
  packw_kernel<<< 9, 256, 0, stream>>>(W4, Wpk4, 18, 6, 2304);

  conv1_kernel<<<512, 256, 0, stream>>>(F, W1, b1, y1);
  stats128_kernel<<<512, 256, 0, stream>>>(y1, stats);
  bn_fin<<<1, 128, 0, stream>>>(stats, g1, be1, ssb, 128, invN);

  conv_mfma<128, 64><<<dim3(512, 7), 256, 0, stream>>>(y1, ssb, Wpk2, b2, y2, stats + 256);
  bn_fin<<<1, 64, 0, stream>>>(stats + 256, g2, be2, ssb + 256, 64, invN);

  conv_mfma<64, 64><<<dim3(512, 7), 256, 0, stream>>>(y2, ssb + 256, Wpk3, b3, y3, stats + 512);
  bn_fin<<<1, 64, 0, stream>>>(stats + 512, g3, be3, ssb + 512, 64, invN);

  conv_mfma<64, 32><<<dim3(512, 7), 256, 0, stream>>>(y3, ssb + 512, Wpk4, b4, y4, stats + 768);
  bn_fin<<<1, 32, 0, stream>>>(stats + 768, g4, be4, ssb + 768, 32, invN);

  woprep_kernel<<<dim3(32, 10), 256, 0, stream>>>(Wo, WoPM);

  act4_kernel<<<3200, 256, 0, stream>>>(y4, ssb + 768, a4);

  lin_init<<<400, 256, 0, stream>>>(bo, lin, 102400);
  linear_kernel<<<dim3(8, 4, 8), 256, 0, stream>>>(a4, WoPM, lin);

  phase_kernel<<<512, 256, 0, stream>>>(lin, Gr, Gi, hrr, hri, accum);
  finalize_kernel<<<1, 1, 0, stream>>>(accum, (float*)d_out);
}

// Round 4
// 333.292 us; speedup vs baseline: 16.4857x; 1.9927x over previous
//
#include <hip/hip_runtime.h>
#include <math.h>

typedef __bf16 bf16x8 __attribute__((ext_vector_type(8)));
typedef float f32x4 __attribute__((ext_vector_type(4)));
typedef unsigned short ushort8 __attribute__((ext_vector_type(8)));

__device__ __forceinline__ float bf2f(unsigned short u){ return __uint_as_float(((unsigned)u) << 16); }
__device__ __forceinline__ unsigned short f2bf(float f){
  unsigned v = __float_as_uint(f);
  return (unsigned short)((v + 0x7FFFu + ((v >> 16) & 1u)) >> 16);
}

// ================= conv1: 2->128 VALU, output pixel-major bf16 =================
__global__ __launch_bounds__(256) void conv1_kernel(
    const float* __restrict__ F, const float* __restrict__ W1, const float* __restrict__ b1,
    unsigned short* __restrict__ y1)
{
  __shared__ float xp[2*484];
  const int tid = threadIdx.x, b = blockIdx.x;
  for (int i = tid; i < 968; i += 256) xp[i] = 0.f;
  __syncthreads();
  for (int i = tid; i < 800; i += 256){
    int ci = i / 400, p = i - ci*400;
    xp[ci*484 + (p/20 + 1)*22 + (p%20) + 1] = F[((size_t)b*2 + ci)*400 + p];
  }
  __syncthreads();
  const int p0 = tid;
  const int p1 = tid + 256;
  const bool v1 = p1 < 400;
  float x0[18], x1[18];
  {
    int h = p0/20, w = p0 - (p0/20)*20;
#pragma unroll
    for (int ci = 0; ci < 2; ++ci)
#pragma unroll
      for (int dh = 0; dh < 3; ++dh)
#pragma unroll
        for (int dw = 0; dw < 3; ++dw)
          x0[ci*9 + dh*3 + dw] = xp[ci*484 + (h+dh)*22 + (w+dw)];
  }
  {
    int pc = v1 ? p1 : 0;
    int h = pc/20, w = pc - (pc/20)*20;
#pragma unroll
    for (int ci = 0; ci < 2; ++ci)
#pragma unroll
      for (int dh = 0; dh < 3; ++dh)
#pragma unroll
        for (int dw = 0; dw < 3; ++dw)
          x1[ci*9 + dh*3 + dw] = xp[ci*484 + (h+dh)*22 + (w+dw)];
  }
  for (int cg = 0; cg < 16; ++cg){
    float a0[8], a1[8];
#pragma unroll
    for (int co = 0; co < 8; ++co){ float bb = b1[cg*8+co]; a0[co] = bb; a1[co] = bb; }
#pragma unroll
    for (int co = 0; co < 8; ++co){
      const float* wq = W1 + (size_t)(cg*8 + co)*18;
#pragma unroll
      for (int k = 0; k < 18; ++k){
        float wv = wq[k];
        a0[co] = fmaf(x0[k], wv, a0[co]);
        a1[co] = fmaf(x1[k], wv, a1[co]);
      }
    }
    union { unsigned short u[8]; uint4 v; } pk;
#pragma unroll
    for (int co = 0; co < 8; ++co) pk.u[co] = f2bf(a0[co]);
    *(uint4*)(y1 + ((size_t)b*400 + p0)*128 + cg*8) = pk.v;
    if (v1){
#pragma unroll
      for (int co = 0; co < 8; ++co) pk.u[co] = f2bf(a1[co]);
      *(uint4*)(y1 + ((size_t)b*400 + p1)*128 + cg*8) = pk.v;
    }
  }
}

// ============ stats over pixel-major [B][400][128] bf16 (layer 1), vectorized ============
__global__ __launch_bounds__(256) void stats128_kernel(const unsigned short* __restrict__ y,
                                                       float* __restrict__ stats)
{
  const int tid = threadIdx.x;
  const int o = tid & 15, pr = tid >> 4;
  float s[8], q[8];
#pragma unroll
  for (int j = 0; j < 8; ++j){ s[j] = 0.f; q[j] = 0.f; }
  const unsigned short* base = y + (size_t)blockIdx.x * 400 * 128;
  for (int p = pr; p < 400; p += 16){
    ushort8 raw = *(const ushort8*)(base + (size_t)p*128 + o*8);
#pragma unroll
    for (int j = 0; j < 8; ++j){ float v = bf2f(raw[j]); s[j] += v; q[j] = fmaf(v, v, q[j]); }
  }
#pragma unroll
  for (int j = 0; j < 8; ++j){
    s[j] += __shfl_xor(s[j], 16); s[j] += __shfl_xor(s[j], 32);
    q[j] += __shfl_xor(q[j], 16); q[j] += __shfl_xor(q[j], 32);
  }
  __shared__ float red[2][4][16][8];
  const int w = tid >> 6, l = tid & 63;
  if ((l >> 4) == 0){
#pragma unroll
    for (int j = 0; j < 8; ++j){ red[0][w][l][j] = s[j]; red[1][w][l][j] = q[j]; }
  }
  __syncthreads();
  {
    int st = tid >> 7, co = tid & 127, oo = co >> 3, j = co & 7;
    float v = red[st][0][oo][j] + red[st][1][oo][j] + red[st][2][oo][j] + red[st][3][oo][j];
    atomicAdd(&stats[st*128 + co], v);
  }
}

// ---------- fold sliced stats -> per-channel scale/shift ----------
__global__ void bn_fin(const float* __restrict__ stats, const float* __restrict__ g,
                       const float* __restrict__ be, float* __restrict__ ss,
                       int C, float invN, int nsl)
{
  int c = threadIdx.x;
  if (c < C){
    float s = 0.f, q = 0.f;
    for (int t = 0; t < nsl; ++t){ s += stats[t*2*C + c]; q += stats[t*2*C + C + c]; }
    float mean = s * invN;
    float var  = q * invN - mean * mean;
    float sc   = g[c] * rsqrtf(var + 1e-5f);
    ss[c]      = sc;
    ss[C + c]  = be[c] - mean * sc;
  }
}

// ---------- weight pack into MFMA A-fragment order ----------
__global__ void packw_kernel(const float* __restrict__ W, unsigned short* __restrict__ Wpk,
                             int KC, int cin_shift, int total)
{
  int idx = blockIdx.x*256 + threadIdx.x;
  if (idx >= total) return;
  int lane = idx & 63, t2 = idx >> 6;
  int kcg = t2 % KC, ct = t2 / KC;
  int co  = ct*16 + (lane & 15);
  int kg0 = kcg*32 + (lane >> 4)*8;
  int CIN = 1 << cin_shift;
#pragma unroll
  for (int j = 0; j < 8; ++j){
    int kg  = kg0 + j;
    int dhw = kg >> cin_shift;
    int ci  = kg & (CIN-1);
    Wpk[(size_t)idx*8 + j] = f2bf(W[((size_t)co*CIN + ci)*9 + dhw]);
  }
}

// ================= MFMA implicit-GEMM conv 3x3 SAME =================
template<int CIN, int COUT>
__global__ __launch_bounds__(256, 4) void conv_mfma(
    const unsigned short* __restrict__ xin, const float* __restrict__ ss_in,
    const unsigned short* __restrict__ Wpk, const float* __restrict__ bconv,
    unsigned short* __restrict__ yout, float* __restrict__ stats)
{
  constexpr int NG   = CIN/8;
  constexpr int LOGNG= (CIN==128) ? 4 : 3;
  constexpr int KC   = (9*CIN)/32;
  constexpr int NSUB = CIN/32;
  constexpr int CT_W = (COUT==64) ? 2 : 1;
  __shared__ unsigned short xs[120*CIN];
  __shared__ float sred[2*COUT];

  const int tid = threadIdx.x;
  const int b = blockIdx.x, t = blockIdx.y;
  const int q0 = t*64;
  const int rb = q0/20 - 1;
  const int wid = tid >> 6, lane = tid & 63, lq = lane >> 4, lr = lane & 15;

  for (int i = tid; i < 2*COUT; i += 256) sred[i] = 0.f;

  {
    const int g = tid & (NG-1);
    const int c = g*8;
    f32x4 s0 = *(const f32x4*)(ss_in + c);
    f32x4 s1 = *(const f32x4*)(ss_in + c + 4);
    f32x4 h0 = *(const f32x4*)(ss_in + CIN + c);
    f32x4 h1 = *(const f32x4*)(ss_in + CIN + c + 4);
    for (int i = tid; i < 120*NG; i += 256){
      int L  = i >> LOGNG;
      int ps = rb*20 + L;
      union { unsigned short u[8]; uint4 v; } pk;
      if (ps >= 0 && ps < 400){
        ushort8 raw = *(const ushort8*)(xin + ((size_t)b*400 + ps)*CIN + c);
        pk.u[0] = f2bf(fmaxf(fmaf(bf2f(raw[0]), s0[0], h0[0]), 0.f));
        pk.u[1] = f2bf(fmaxf(fmaf(bf2f(raw[1]), s0[1], h0[1]), 0.f));
        pk.u[2] = f2bf(fmaxf(fmaf(bf2f(raw[2]), s0[2], h0[2]), 0.f));
        pk.u[3] = f2bf(fmaxf(fmaf(bf2f(raw[3]), s0[3], h0[3]), 0.f));
        pk.u[4] = f2bf(fmaxf(fmaf(bf2f(raw[4]), s1[0], h1[0]), 0.f));
        pk.u[5] = f2bf(fmaxf(fmaf(bf2f(raw[5]), s1[1], h1[1]), 0.f));
        pk.u[6] = f2bf(fmaxf(fmaf(bf2f(raw[6]), s1[2], h1[2]), 0.f));
        pk.u[7] = f2bf(fmaxf(fmaf(bf2f(raw[7]), s1[3], h1[3]), 0.f));
      } else {
        pk.v.x = 0u; pk.v.y = 0u; pk.v.z = 0u; pk.v.w = 0u;
      }
      *(uint4*)&xs[(size_t)((L << LOGNG) + (g ^ (L & 7)))*8] = pk.v;
    }
  }
  __syncthreads();

  const int ct0 = (wid & 1) * CT_W;
  const int pt0 = (wid >> 1) * 2;
  int Lq[2], px[2]; bool mL[2], mR[2];
#pragma unroll
  for (int k2 = 0; k2 < 2; ++k2){
    int q = q0 + (pt0 + k2)*16 + lr;
    px[k2] = q;
    int w  = q % 20;
    mL[k2] = (w == 0); mR[k2] = (w == 19);
    Lq[k2] = q - 20*rb;
  }
  f32x4 acc[CT_W][2];
#pragma unroll
  for (int c2 = 0; c2 < CT_W; ++c2)
#pragma unroll
    for (int k2 = 0; k2 < 2; ++k2){ acc[c2][k2][0]=0.f; acc[c2][k2][1]=0.f; acc[c2][k2][2]=0.f; acc[c2][k2][3]=0.f; }

#pragma unroll 3
  for (int dhw = 0; dhw < 9; ++dhw){
    const int dr = dhw/3 - 1, dc = dhw%3 - 1;
    const int doff = dr*20 + dc;
#pragma unroll
    for (int sub = 0; sub < NSUB; ++sub){
      bf16x8 af[CT_W];
#pragma unroll
      for (int c2 = 0; c2 < CT_W; ++c2)
        af[c2] = *(const bf16x8*)(Wpk + (((size_t)((ct0+c2)*KC + dhw*NSUB + sub)*64 + lane) << 3));
      bf16x8 bf[2];
#pragma unroll
      for (int k2 = 0; k2 < 2; ++k2){
        int Lt = Lq[k2] + doff;
        Lt = Lt < 0 ? 0 : (Lt > 119 ? 119 : Lt);
        int addr = (Lt << LOGNG) + ((sub*4 + lq) ^ (Lt & 7));
        union { uint4 v; bf16x8 h; } u;
        u.h = *(const bf16x8*)&xs[(size_t)addr*8];
        if (dc != 0){
          bool dead = (dc < 0) ? mL[k2] : mR[k2];
          unsigned keep = dead ? 0u : 0xFFFFFFFFu;
          u.v.x &= keep; u.v.y &= keep; u.v.z &= keep; u.v.w &= keep;
        }
        bf[k2] = u.h;
      }
#pragma unroll
      for (int c2 = 0; c2 < CT_W; ++c2)
#pragma unroll
        for (int k2 = 0; k2 < 2; ++k2)
          acc[c2][k2] = __builtin_amdgcn_mfma_f32_16x16x32_bf16(af[c2], bf[k2], acc[c2][k2], 0, 0, 0);
    }
  }

  float smv[CT_W][4], sqv[CT_W][4];
#pragma unroll
  for (int c2 = 0; c2 < CT_W; ++c2)
#pragma unroll
    for (int r = 0; r < 4; ++r){ smv[c2][r] = 0.f; sqv[c2][r] = 0.f; }

#pragma unroll
  for (int c2 = 0; c2 < CT_W; ++c2){
    f32x4 bias = *(const f32x4*)(bconv + (ct0+c2)*16 + lq*4);
#pragma unroll
    for (int k2 = 0; k2 < 2; ++k2){
      bool ok = px[k2] < 400;
      f32x4 y = acc[c2][k2] + bias;
      union { unsigned short u[4]; unsigned long long ll; } pk;
#pragma unroll
      for (int r = 0; r < 4; ++r){
        float yv = ok ? y[r] : 0.f;
        pk.u[r] = f2bf(y[r]);
        smv[c2][r] += yv;
        sqv[c2][r] = fmaf(yv, yv, sqv[c2][r]);
      }
      if (ok)
        *(unsigned long long*)(yout + ((size_t)b*400 + px[k2])*COUT + (ct0+c2)*16 + lq*4) = pk.ll;
    }
  }
#pragma unroll
  for (int c2 = 0; c2 < CT_W; ++c2)
#pragma unroll
    for (int r = 0; r < 4; ++r){
      float v = smv[c2][r], w2 = sqv[c2][r];
#pragma unroll
      for (int m = 1; m < 16; m <<= 1){ v += __shfl_xor(v, m); w2 += __shfl_xor(w2, m); }
      if (lr == 0){
        int co = (ct0+c2)*16 + lq*4 + r;
        atomicAdd(&sred[co], v);
        atomicAdd(&sred[COUT + co], w2);
      }
    }
  __syncthreads();
  float* st = stats + (size_t)(t & 3) * 2 * COUT;
  for (int i = tid; i < 2*COUT; i += 256)
    atomicAdd(&st[i], sred[i]);
}

// ---------- pack/permute Wo[j][c*400+p] -> Wob[j][p*32+c] bf16, rows 200..255 zero ----------
__global__ __launch_bounds__(256) void wopack_kernel(const float* __restrict__ Wo,
                                                     unsigned short* __restrict__ Wob)
{
  __shared__ float row[12800];
  const int j = blockIdx.x, tid = threadIdx.x;
  if (j < 200){
    const float4* src = (const float4*)(Wo + (size_t)j*12800);
    for (int i = tid; i < 3200; i += 256) ((float4*)row)[i] = src[i];
    __syncthreads();
    for (int ko = tid; ko < 1600; ko += 256){
      int p = ko >> 2, c0 = (ko & 3)*8;
      union { unsigned short u[8]; uint4 v; } pk;
#pragma unroll
      for (int t = 0; t < 8; ++t) pk.u[t] = f2bf(row[(c0+t)*400 + p]);
      *(uint4*)(Wob + (size_t)j*12800 + ko*8) = pk.v;
    }
  } else {
    uint4 z = {0,0,0,0};
    for (int ko = tid; ko < 1600; ko += 256)
      *(uint4*)(Wob + (size_t)j*12800 + ko*8) = z;
  }
}

// ================= linear: MFMA split-K, BN+ReLU(y4) fused into A-stage =================
// C[m=b][j] partial over K-chunk z -> lin_z[z][512][208] f32
__global__ __launch_bounds__(256, 4) void linear_mfma(
    const unsigned short* __restrict__ y4, const float* __restrict__ ss4,
    const unsigned short* __restrict__ Wob, float* __restrict__ lin_z)
{
  __shared__ unsigned short As[64*128];
  __shared__ unsigned short Bs[64*128];
  const int tid = threadIdx.x;
  const int m0 = blockIdx.x * 64;
  const int j0 = blockIdx.y * 64;
  const int z  = blockIdx.z;
  const int wid = tid >> 6, lane = tid & 63, lq = lane >> 4, lr = lane & 15;
  const int srow = tid >> 4, soct = tid & 15;
  const int c0 = (soct & 3) * 8;

  f32x4 s0 = *(const f32x4*)(ss4 + c0);
  f32x4 s1 = *(const f32x4*)(ss4 + c0 + 4);
  f32x4 h0 = *(const f32x4*)(ss4 + 32 + c0);
  f32x4 h1 = *(const f32x4*)(ss4 + 32 + c0 + 4);

  f32x4 acc[4];
#pragma unroll
  for (int ct = 0; ct < 4; ++ct){ acc[ct][0]=0.f; acc[ct][1]=0.f; acc[ct][2]=0.f; acc[ct][3]=0.f; }

  for (int ch = 0; ch < 4; ++ch){
    const int k0 = z*512 + ch*128;
    __syncthreads();
#pragma unroll
    for (int pass = 0; pass < 4; ++pass){
      int row = pass*16 + srow;
      ushort8 raw = *(const ushort8*)(y4 + (size_t)(m0+row)*12800 + k0 + soct*8);
      union { unsigned short u[8]; uint4 v; } pk;
      pk.u[0] = f2bf(fmaxf(fmaf(bf2f(raw[0]), s0[0], h0[0]), 0.f));
      pk.u[1] = f2bf(fmaxf(fmaf(bf2f(raw[1]), s0[1], h0[1]), 0.f));
      pk.u[2] = f2bf(fmaxf(fmaf(bf2f(raw[2]), s0[2], h0[2]), 0.f));
      pk.u[3] = f2bf(fmaxf(fmaf(bf2f(raw[3]), s0[3], h0[3]), 0.f));
      pk.u[4] = f2bf(fmaxf(fmaf(bf2f(raw[4]), s1[0], h1[0]), 0.f));
      pk.u[5] = f2bf(fmaxf(fmaf(bf2f(raw[5]), s1[1], h1[1]), 0.f));
      pk.u[6] = f2bf(fmaxf(fmaf(bf2f(raw[6]), s1[2], h1[2]), 0.f));
      pk.u[7] = f2bf(fmaxf(fmaf(bf2f(raw[7]), s1[3], h1[3]), 0.f));
      *(uint4*)&As[(size_t)((row << 4) + (soct ^ (row & 7)))*8] = pk.v;
      uint4 wv = *(const uint4*)(Wob + (size_t)(j0+row)*12800 + k0 + soct*8);
      *(uint4*)&Bs[(size_t)((row << 4) + (soct ^ (row & 7)))*8] = wv;
    }
    __syncthreads();
#pragma unroll
    for (int ks = 0; ks < 4; ++ks){
      const int arow = wid*16 + lr;
      bf16x8 afr = *(const bf16x8*)&As[(size_t)((arow << 4) + ((ks*4 + lq) ^ (arow & 7)))*8];
#pragma unroll
      for (int ct = 0; ct < 4; ++ct){
        const int brow = ct*16 + lr;
        bf16x8 bfr = *(const bf16x8*)&Bs[(size_t)((brow << 4) + ((ks*4 + lq) ^ (brow & 7)))*8];
        acc[ct] = __builtin_amdgcn_mfma_f32_16x16x32_bf16(afr, bfr, acc[ct], 0, 0, 0);
      }
    }
  }
#pragma unroll
  for (int ct = 0; ct < 4; ++ct){
    int j = j0 + ct*16 + lr;
    if (j < 208){
#pragma unroll
      for (int r = 0; r < 4; ++r){
        int m = m0 + wid*16 + lq*4 + r;
        lin_z[((size_t)z*512 + m)*208 + j] = acc[ct][r];
      }
    }
  }
}

// ---------- phase + einsum + norm (with fused split-K reduction + bias) ----------
__global__ __launch_bounds__(256) void phase_kernel(const float* __restrict__ lin_z,
                                                    const float* __restrict__ bo,
                                                    const float* __restrict__ Gr,
                                                    const float* __restrict__ Gi,
                                                    const float* __restrict__ hrr,
                                                    const float* __restrict__ hri,
                                                    float* __restrict__ accum)
{
  const int b = blockIdx.x;
  const int tid = threadIdx.x;
  __shared__ float lsh[200];
  __shared__ float u[100];
  __shared__ float pp[100];
  __shared__ float redbuf[4];
  if (tid < 200){
    float a = bo[tid];
#pragma unroll 5
    for (int z = 0; z < 25; ++z)
      a += lin_z[((size_t)z*512 + b)*208 + tid];
    lsh[tid] = a;
  }
  __syncthreads();
  if (tid < 100){
    float c = cosf(lsh[tid]);
    float s = sinf(lsh[100 + tid]);
    float hr = hrr[b*100 + tid];
    float hi = hri[b*100 + tid];
    u[tid]  = c*hr - s*hi;
    pp[tid] = c*hi + s*hr;
  }
  __syncthreads();
  const int m = tid;
  const float4* grow  = (const float4*)(Gr + ((size_t)b*256 + m)*100);
  const float4* girow = (const float4*)(Gi + ((size_t)b*256 + m)*100);
  float tr = 0.f, ti = 0.f;
#pragma unroll
  for (int i = 0; i < 25; ++i){
    float4 g  = grow[i];
    float4 gg = girow[i];
    float4 uu = *(const float4*)&u[i*4];
    float4 qq = *(const float4*)&pp[i*4];
    tr += g.x*uu.x - gg.x*qq.x;  ti += g.x*qq.x + gg.x*uu.x;
    tr += g.y*uu.y - gg.y*qq.y;  ti += g.y*qq.y + gg.y*uu.y;
    tr += g.z*uu.z - gg.z*qq.z;  ti += g.z*qq.z + gg.z*uu.z;
    tr += g.w*uu.w - gg.w*qq.w;  ti += g.w*qq.w + gg.w*uu.w;
  }
  float ns = tr*tr + ti*ti;
#pragma unroll
  for (int off = 32; off; off >>= 1) ns += __shfl_down(ns, off);
  if ((tid & 63) == 0) redbuf[tid >> 6] = ns;
  __syncthreads();
  if (tid == 0) atomicAdd(accum, redbuf[0] + redbuf[1] + redbuf[2] + redbuf[3]);
}

__global__ void finalize_kernel(const float* __restrict__ accum, float* __restrict__ out)
{
  out[0] = -accum[0] * (1.0f / 512.0f);
}

extern "C" void kernel_launch(void* const* d_in, const int* in_sizes, int n_in,
                              void* d_out, int out_size, void* d_ws, size_t ws_size,
                              hipStream_t stream)
{
  const float* F   = (const float*)d_in[0];
  const float* Gr  = (const float*)d_in[1];
  const float* Gi  = (const float*)d_in[2];
  const float* hrr = (const float*)d_in[3];
  const float* hri = (const float*)d_in[4];
  const float* W1  = (const float*)d_in[5];
  const float* b1  = (const float*)d_in[6];
  const float* g1  = (const float*)d_in[7];
  const float* be1 = (const float*)d_in[8];
  const float* W2  = (const float*)d_in[9];
  const float* b2  = (const float*)d_in[10];
  const float* g2  = (const float*)d_in[11];
  const float* be2 = (const float*)d_in[12];
  const float* W3  = (const float*)d_in[13];
  const float* b3  = (const float*)d_in[14];
  const float* g3  = (const float*)d_in[15];
  const float* be3 = (const float*)d_in[16];
  const float* W4  = (const float*)d_in[17];
  const float* b4  = (const float*)d_in[18];
  const float* g4  = (const float*)d_in[19];
  const float* be4 = (const float*)d_in[20];
  const float* Wo  = (const float*)d_in[21];
  const float* bo  = (const float*)d_in[22];

  char* ws = (char*)d_ws;
  // region A (0..52,428,800): y1 full; later y3 (26.2MB) then lin_z at +13,107,200
  // region B (52,428,800..78,643,200): y2 full; later y4 (13.1MB) + Wob at 65,536,000
  unsigned short* y1   = (unsigned short*)(ws);
  unsigned short* y2   = (unsigned short*)(ws + 52428800);
  unsigned short* y3   = (unsigned short*)(ws);
  unsigned short* y4   = (unsigned short*)(ws + 52428800);
  unsigned short* Wob  = (unsigned short*)(ws + 65536000);   // 256x12800 bf16 = 6,553,600
  float*          lin_z= (float*)(ws + 13107200);            // 25x512x208 f32 = 10,649,600
  float* stats = (float*)(ws + 78643200);                    // 1536 f32 = 6144 B
  float* ssb   = (float*)(ws + 78649344);                    // 1024 f32 = 4096 B
  float* accum = (float*)(ws + 78653440);                    // 16 B
  unsigned short* Wpk2 = (unsigned short*)(ws + 78653456);   // 147,456
  unsigned short* Wpk3 = (unsigned short*)(ws + 78800912);   //  73,728
  unsigned short* Wpk4 = (unsigned short*)(ws + 78874640);   //  36,864 -> end 78,911,504

  hipMemsetAsync(ws + 78643200, 0, 10256, stream);  // stats + ssb + accum

  const float invN = 1.0f / 204800.0f;

  packw_kernel<<<36, 256, 0, stream>>>(W2, Wpk2, 36, 7, 9216);
  packw_kernel<<<18, 256, 0, stream>>>(W3, Wpk3, 18, 6, 4608);
  packw_kernel<<< 9, 256, 0, stream>>>(W4, Wpk4, 18, 6, 2304);

  conv1_kernel<<<512, 256, 0, stream>>>(F, W1, b1, y1);
  stats128_kernel<<<512, 256, 0, stream>>>(y1, stats);
  bn_fin<<<1, 128, 0, stream>>>(stats, g1, be1, ssb, 128, invN, 1);

  conv_mfma<128, 64><<<dim3(512, 7), 256, 0, stream>>>(y1, ssb, Wpk2, b2, y2, stats + 256);
  bn_fin<<<1, 64, 0, stream>>>(stats + 256, g2, be2, ssb + 256, 64, invN, 4);

  conv_mfma<64, 64><<<dim3(512, 7), 256, 0, stream>>>(y2, ssb + 256, Wpk3, b3, y3, stats + 768);
  bn_fin<<<1, 64, 0, stream>>>(stats + 768, g3, be3, ssb + 384, 64, invN, 4);

  conv_mfma<64, 32><<<dim3(512, 7), 256, 0, stream>>>(y3, ssb + 384, Wpk4, b4, y4, stats + 1280);
  bn_fin<<<1, 32, 0, stream>>>(stats + 1280, g4, be4, ssb + 512, 32, invN, 4);

  // Wob pack (y2 dead after conv3; write overlaps old y2 tail only)
  wopack_kernel<<<256, 256, 0, stream>>>(Wo, Wob);

  // linear: split-K MFMA (reads y4 + ss4, writes lin_z in region A after y3 dead)
  linear_mfma<<<dim3(8, 4, 25), 256, 0, stream>>>(y4, ssb + 512, Wob, lin_z);

  phase_kernel<<<512, 256, 0, stream>>>(lin_z, bo, Gr, Gi, hrr, hri, accum);
  finalize_kernel<<<1, 1, 0, stream>>>(accum, (float*)d_out);
}

// Round 5
// 324.758 us; speedup vs baseline: 16.9190x; 1.0263x over previous
//
#include <hip/hip_runtime.h>
#include <math.h>

typedef __bf16 bf16x8 __attribute__((ext_vector_type(8)));
typedef float f32x4 __attribute__((ext_vector_type(4)));
typedef unsigned short ushort8 __attribute__((ext_vector_type(8)));

__device__ __forceinline__ float bf2f(unsigned short u){ return __uint_as_float(((unsigned)u) << 16); }
__device__ __forceinline__ unsigned short f2bf(float f){
  unsigned v = __float_as_uint(f);
  return (unsigned short)((v + 0x7FFFu + ((v >> 16) & 1u)) >> 16);
}

// ================= conv1 v2: 2->128 VALU, coalesced pixel-major store + fused stats =================
// grid (512, 2): block = half image (200 px). LDS-buffered output, bank-staggered stride 130.
__global__ __launch_bounds__(256, 2) void conv1_kernel(
    const float* __restrict__ F, const float* __restrict__ W1, const float* __restrict__ b1,
    unsigned short* __restrict__ y1, float* __restrict__ stats)
{
  __shared__ float xp[2][12][22];            // rows r0-1..r0+10, cols pad
  __shared__ unsigned short ybuf[200*130];   // [px][c] stride 130
  __shared__ float red[2][4][16][8];         // [s/q][wave][oct][j]
  const int tid = threadIdx.x, b = blockIdx.x, half = blockIdx.y;
  const int r0 = half*10;

  for (int i = tid; i < 2*12*22; i += 256) ((float*)xp)[i] = 0.f;
  __syncthreads();
  for (int i = tid; i < 2*12*20; i += 256){
    int ci = i / 240, rr = (i / 20) % 12, cc2 = i % 20;
    int gr = r0 - 1 + rr;
    if (gr >= 0 && gr < 20)
      xp[ci][rr][cc2+1] = F[((size_t)b*2 + ci)*400 + gr*20 + cc2];
  }
  __syncthreads();

  if (tid < 200){
    const int h = tid/20, w = tid - (tid/20)*20;
    float x[18];
#pragma unroll
    for (int ci = 0; ci < 2; ++ci)
#pragma unroll
      for (int dh = 0; dh < 3; ++dh)
#pragma unroll
        for (int dw = 0; dw < 3; ++dw)
          x[ci*9 + dh*3 + dw] = xp[ci][h+dh][w+dw];
#pragma unroll 2
    for (int cg = 0; cg < 16; ++cg){
      float a0[8];
#pragma unroll
      for (int co = 0; co < 8; ++co) a0[co] = b1[cg*8+co];
#pragma unroll
      for (int co = 0; co < 8; ++co){
        const float* wq = W1 + (size_t)(cg*8 + co)*18;
#pragma unroll
        for (int k = 0; k < 18; ++k) a0[co] = fmaf(x[k], wq[k], a0[co]);
      }
      union { unsigned short u[8]; uint4 v; } pk;
#pragma unroll
      for (int co = 0; co < 8; ++co) pk.u[co] = f2bf(a0[co]);
      *(uint4*)&ybuf[tid*130 + cg*8] = pk.v;
    }
  }
  __syncthreads();

  // coalesced write-out + fused per-channel stats (oct = tid&15 constant per thread)
  float s[8], q[8];
#pragma unroll
  for (int j = 0; j < 8; ++j){ s[j] = 0.f; q[j] = 0.f; }
  for (int i = tid; i < 3200; i += 256){
    int px = i >> 4, oct = i & 15;
    union { uint4 v; unsigned short u[8]; } pk;
    pk.v = *(const uint4*)&ybuf[px*130 + oct*8];
#pragma unroll
    for (int j = 0; j < 8; ++j){ float v = bf2f(pk.u[j]); s[j] += v; q[j] = fmaf(v, v, q[j]); }
    *(uint4*)(y1 + ((size_t)b*400 + half*200 + px)*128 + oct*8) = pk.v;
  }
#pragma unroll
  for (int j = 0; j < 8; ++j){
    s[j] += __shfl_xor(s[j], 16); s[j] += __shfl_xor(s[j], 32);
    q[j] += __shfl_xor(q[j], 16); q[j] += __shfl_xor(q[j], 32);
  }
  const int wv = tid >> 6, l = tid & 63;
  if ((l >> 4) == 0){
#pragma unroll
    for (int j = 0; j < 8; ++j){ red[0][wv][l][j] = s[j]; red[1][wv][l][j] = q[j]; }
  }
  __syncthreads();
  {
    int st = tid >> 7, co = tid & 127, oo = co >> 3, j = co & 7;
    float v = red[st][0][oo][j] + red[st][1][oo][j] + red[st][2][oo][j] + red[st][3][oo][j];
    atomicAdd(&stats[st*128 + co], v);
  }
}

// ---------- fold sliced stats -> per-channel scale/shift ----------
__global__ void bn_fin(const float* __restrict__ stats, const float* __restrict__ g,
                       const float* __restrict__ be, float* __restrict__ ss,
                       int C, float invN, int nsl)
{
  int c = threadIdx.x;
  if (c < C){
    float s = 0.f, q = 0.f;
    for (int t = 0; t < nsl; ++t){ s += stats[t*2*C + c]; q += stats[t*2*C + C + c]; }
    float mean = s * invN;
    float var  = q * invN - mean * mean;
    float sc   = g[c] * rsqrtf(var + 1e-5f);
    ss[c]      = sc;
    ss[C + c]  = be[c] - mean * sc;
  }
}

// ---------- weight pack into MFMA A-fragment order ----------
__global__ void packw_kernel(const float* __restrict__ W, unsigned short* __restrict__ Wpk,
                             int KC, int cin_shift, int total)
{
  int idx = blockIdx.x*256 + threadIdx.x;
  if (idx >= total) return;
  int lane = idx & 63, t2 = idx >> 6;
  int kcg = t2 % KC, ct = t2 / KC;
  int co  = ct*16 + (lane & 15);
  int kg0 = kcg*32 + (lane >> 4)*8;
  int CIN = 1 << cin_shift;
#pragma unroll
  for (int j = 0; j < 8; ++j){
    int kg  = kg0 + j;
    int dhw = kg >> cin_shift;
    int ci  = kg & (CIN-1);
    Wpk[(size_t)idx*8 + j] = f2bf(W[((size_t)co*CIN + ci)*9 + dhw]);
  }
}

// ================= MFMA implicit-GEMM conv 3x3 SAME =================
template<int CIN, int COUT, int NBLK>
__global__ __launch_bounds__(256, NBLK) void conv_mfma(
    const unsigned short* __restrict__ xin, const float* __restrict__ ss_in,
    const unsigned short* __restrict__ Wpk, const float* __restrict__ bconv,
    unsigned short* __restrict__ yout, float* __restrict__ stats)
{
  constexpr int NG   = CIN/8;
  constexpr int LOGNG= (CIN==128) ? 4 : 3;
  constexpr int KC   = (9*CIN)/32;
  constexpr int NSUB = CIN/32;
  constexpr int CT_W = (COUT==64) ? 2 : 1;
  __shared__ unsigned short xs[120*CIN];
  __shared__ float sred[2*COUT];

  const int tid = threadIdx.x;
  const int b = blockIdx.x, t = blockIdx.y;
  const int q0 = t*64;
  const int rb = q0/20 - 1;
  const int wid = tid >> 6, lane = tid & 63, lq = lane >> 4, lr = lane & 15;

  for (int i = tid; i < 2*COUT; i += 256) sred[i] = 0.f;

  {
    const int g = tid & (NG-1);
    const int c = g*8;
    f32x4 s0 = *(const f32x4*)(ss_in + c);
    f32x4 s1 = *(const f32x4*)(ss_in + c + 4);
    f32x4 h0 = *(const f32x4*)(ss_in + CIN + c);
    f32x4 h1 = *(const f32x4*)(ss_in + CIN + c + 4);
    for (int i = tid; i < 120*NG; i += 256){
      int L  = i >> LOGNG;
      int ps = rb*20 + L;
      union { unsigned short u[8]; uint4 v; } pk;
      if (ps >= 0 && ps < 400){
        ushort8 raw = *(const ushort8*)(xin + ((size_t)b*400 + ps)*CIN + c);
        pk.u[0] = f2bf(fmaxf(fmaf(bf2f(raw[0]), s0[0], h0[0]), 0.f));
        pk.u[1] = f2bf(fmaxf(fmaf(bf2f(raw[1]), s0[1], h0[1]), 0.f));
        pk.u[2] = f2bf(fmaxf(fmaf(bf2f(raw[2]), s0[2], h0[2]), 0.f));
        pk.u[3] = f2bf(fmaxf(fmaf(bf2f(raw[3]), s0[3], h0[3]), 0.f));
        pk.u[4] = f2bf(fmaxf(fmaf(bf2f(raw[4]), s1[0], h1[0]), 0.f));
        pk.u[5] = f2bf(fmaxf(fmaf(bf2f(raw[5]), s1[1], h1[1]), 0.f));
        pk.u[6] = f2bf(fmaxf(fmaf(bf2f(raw[6]), s1[2], h1[2]), 0.f));
        pk.u[7] = f2bf(fmaxf(fmaf(bf2f(raw[7]), s1[3], h1[3]), 0.f));
      } else {
        pk.v.x = 0u; pk.v.y = 0u; pk.v.z = 0u; pk.v.w = 0u;
      }
      *(uint4*)&xs[(size_t)((L << LOGNG) + (g ^ (L & 7)))*8] = pk.v;
    }
  }
  __syncthreads();

  const int ct0 = (wid & 1) * CT_W;
  const int pt0 = (wid >> 1) * 2;
  int Lq[2], px[2]; bool mL[2], mR[2];
#pragma unroll
  for (int k2 = 0; k2 < 2; ++k2){
    int q = q0 + (pt0 + k2)*16 + lr;
    px[k2] = q;
    int w  = q % 20;
    mL[k2] = (w == 0); mR[k2] = (w == 19);
    Lq[k2] = q - 20*rb;
  }
  f32x4 acc[CT_W][2];
#pragma unroll
  for (int c2 = 0; c2 < CT_W; ++c2)
#pragma unroll
    for (int k2 = 0; k2 < 2; ++k2){ acc[c2][k2][0]=0.f; acc[c2][k2][1]=0.f; acc[c2][k2][2]=0.f; acc[c2][k2][3]=0.f; }

#pragma unroll 3
  for (int dhw = 0; dhw < 9; ++dhw){
    const int dr = dhw/3 - 1, dc = dhw%3 - 1;
    const int doff = dr*20 + dc;
#pragma unroll
    for (int sub = 0; sub < NSUB; ++sub){
      bf16x8 af[CT_W];
#pragma unroll
      for (int c2 = 0; c2 < CT_W; ++c2)
        af[c2] = *(const bf16x8*)(Wpk + (((size_t)((ct0+c2)*KC + dhw*NSUB + sub)*64 + lane) << 3));
      bf16x8 bf[2];
#pragma unroll
      for (int k2 = 0; k2 < 2; ++k2){
        int Lt = Lq[k2] + doff;
        Lt = Lt < 0 ? 0 : (Lt > 119 ? 119 : Lt);
        int addr = (Lt << LOGNG) + ((sub*4 + lq) ^ (Lt & 7));
        union { uint4 v; bf16x8 h; } u;
        u.h = *(const bf16x8*)&xs[(size_t)addr*8];
        if (dc != 0){
          bool dead = (dc < 0) ? mL[k2] : mR[k2];
          unsigned keep = dead ? 0u : 0xFFFFFFFFu;
          u.v.x &= keep; u.v.y &= keep; u.v.z &= keep; u.v.w &= keep;
        }
        bf[k2] = u.h;
      }
#pragma unroll
      for (int c2 = 0; c2 < CT_W; ++c2)
#pragma unroll
        for (int k2 = 0; k2 < 2; ++k2)
          acc[c2][k2] = __builtin_amdgcn_mfma_f32_16x16x32_bf16(af[c2], bf[k2], acc[c2][k2], 0, 0, 0);
    }
  }

  float smv[CT_W][4], sqv[CT_W][4];
#pragma unroll
  for (int c2 = 0; c2 < CT_W; ++c2)
#pragma unroll
    for (int r = 0; r < 4; ++r){ smv[c2][r] = 0.f; sqv[c2][r] = 0.f; }

#pragma unroll
  for (int c2 = 0; c2 < CT_W; ++c2){
    f32x4 bias = *(const f32x4*)(bconv + (ct0+c2)*16 + lq*4);
#pragma unroll
    for (int k2 = 0; k2 < 2; ++k2){
      bool ok = px[k2] < 400;
      f32x4 y = acc[c2][k2] + bias;
      union { unsigned short u[4]; unsigned long long ll; } pk;
#pragma unroll
      for (int r = 0; r < 4; ++r){
        float yv = ok ? y[r] : 0.f;
        pk.u[r] = f2bf(y[r]);
        smv[c2][r] += yv;
        sqv[c2][r] = fmaf(yv, yv, sqv[c2][r]);
      }
      if (ok)
        *(unsigned long long*)(yout + ((size_t)b*400 + px[k2])*COUT + (ct0+c2)*16 + lq*4) = pk.ll;
    }
  }
#pragma unroll
  for (int c2 = 0; c2 < CT_W; ++c2)
#pragma unroll
    for (int r = 0; r < 4; ++r){
      float v = smv[c2][r], w2 = sqv[c2][r];
#pragma unroll
      for (int m = 1; m < 16; m <<= 1){ v += __shfl_xor(v, m); w2 += __shfl_xor(w2, m); }
      if (lr == 0){
        int co = (ct0+c2)*16 + lq*4 + r;
        atomicAdd(&sred[co], v);
        atomicAdd(&sred[COUT + co], w2);
      }
    }
  __syncthreads();
  float* st = stats + (size_t)(t & 3) * 2 * COUT;
  for (int i = tid; i < 2*COUT; i += 256)
    atomicAdd(&st[i], sred[i]);
}

// ---------- pack/permute Wo[j][c*400+p] -> Wob[j][p*32+c] bf16, rows 200..255 zero ----------
__global__ __launch_bounds__(256) void wopack_kernel(const float* __restrict__ Wo,
                                                     unsigned short* __restrict__ Wob)
{
  __shared__ float row[12800];
  const int j = blockIdx.x, tid = threadIdx.x;
  if (j < 200){
    const float4* src = (const float4*)(Wo + (size_t)j*12800);
    for (int i = tid; i < 3200; i += 256) ((float4*)row)[i] = src[i];
    __syncthreads();
    for (int ko = tid; ko < 1600; ko += 256){
      int p = ko >> 2, c0 = (ko & 3)*8;
      union { unsigned short u[8]; uint4 v; } pk;
#pragma unroll
      for (int t = 0; t < 8; ++t) pk.u[t] = f2bf(row[(c0+t)*400 + p]);
      *(uint4*)(Wob + (size_t)j*12800 + ko*8) = pk.v;
    }
  } else {
    uint4 z = {0,0,0,0};
    for (int ko = tid; ko < 1600; ko += 256)
      *(uint4*)(Wob + (size_t)j*12800 + ko*8) = z;
  }
}

// ================= linear: MFMA split-K, BN+ReLU(y4) fused into A-stage =================
__global__ __launch_bounds__(256, 4) void linear_mfma(
    const unsigned short* __restrict__ y4, const float* __restrict__ ss4,
    const unsigned short* __restrict__ Wob, float* __restrict__ lin_z)
{
  __shared__ unsigned short As[64*128];
  __shared__ unsigned short Bs[64*128];
  const int tid = threadIdx.x;
  const int m0 = blockIdx.x * 64;
  const int j0 = blockIdx.y * 64;
  const int z  = blockIdx.z;
  const int wid = tid >> 6, lane = tid & 63, lq = lane >> 4, lr = lane & 15;
  const int srow = tid >> 4, soct = tid & 15;
  const int c0 = (soct & 3) * 8;

  f32x4 s0 = *(const f32x4*)(ss4 + c0);
  f32x4 s1 = *(const f32x4*)(ss4 + c0 + 4);
  f32x4 h0 = *(const f32x4*)(ss4 + 32 + c0);
  f32x4 h1 = *(const f32x4*)(ss4 + 32 + c0 + 4);

  f32x4 acc[4];
#pragma unroll
  for (int ct = 0; ct < 4; ++ct){ acc[ct][0]=0.f; acc[ct][1]=0.f; acc[ct][2]=0.f; acc[ct][3]=0.f; }

  for (int ch = 0; ch < 4; ++ch){
    const int k0 = z*512 + ch*128;
    __syncthreads();
#pragma unroll
    for (int pass = 0; pass < 4; ++pass){
      int row = pass*16 + srow;
      ushort8 raw = *(const ushort8*)(y4 + (size_t)(m0+row)*12800 + k0 + soct*8);
      union { unsigned short u[8]; uint4 v; } pk;
      pk.u[0] = f2bf(fmaxf(fmaf(bf2f(raw[0]), s0[0], h0[0]), 0.f));
      pk.u[1] = f2bf(fmaxf(fmaf(bf2f(raw[1]), s0[1], h0[1]), 0.f));
      pk.u[2] = f2bf(fmaxf(fmaf(bf2f(raw[2]), s0[2], h0[2]), 0.f));
      pk.u[3] = f2bf(fmaxf(fmaf(bf2f(raw[3]), s0[3], h0[3]), 0.f));
      pk.u[4] = f2bf(fmaxf(fmaf(bf2f(raw[4]), s1[0], h1[0]), 0.f));
      pk.u[5] = f2bf(fmaxf(fmaf(bf2f(raw[5]), s1[1], h1[1]), 0.f));
      pk.u[6] = f2bf(fmaxf(fmaf(bf2f(raw[6]), s1[2], h1[2]), 0.f));
      pk.u[7] = f2bf(fmaxf(fmaf(bf2f(raw[7]), s1[3], h1[7 & 3]), 0.f));
      pk.u[7] = f2bf(fmaxf(fmaf(bf2f(raw[7]), s1[3], h1[3]), 0.f));
      *(uint4*)&As[(size_t)((row << 4) + (soct ^ (row & 7)))*8] = pk.v;
      uint4 wv = *(const uint4*)(Wob + (size_t)(j0+row)*12800 + k0 + soct*8);
      *(uint4*)&Bs[(size_t)((row << 4) + (soct ^ (row & 7)))*8] = wv;
    }
    __syncthreads();
#pragma unroll
    for (int ks = 0; ks < 4; ++ks){
      const int arow = wid*16 + lr;
      bf16x8 afr = *(const bf16x8*)&As[(size_t)((arow << 4) + ((ks*4 + lq) ^ (arow & 7)))*8];
#pragma unroll
      for (int ct = 0; ct < 4; ++ct){
        const int brow = ct*16 + lr;
        bf16x8 bfr = *(const bf16x8*)&Bs[(size_t)((brow << 4) + ((ks*4 + lq) ^ (brow & 7)))*8];
        acc[ct] = __builtin_amdgcn_mfma_f32_16x16x32_bf16(afr, bfr, acc[ct], 0, 0, 0);
      }
    }
  }
#pragma unroll
  for (int ct = 0; ct < 4; ++ct){
    int j = j0 + ct*16 + lr;
    if (j < 208){
#pragma unroll
      for (int r = 0; r < 4; ++r){
        int m = m0 + wid*16 + lq*4 + r;
        lin_z[((size_t)z*512 + m)*208 + j] = acc[ct][r];
      }
    }
  }
}

// ---------- phase + einsum + norm (with fused split-K reduction + bias) ----------
__global__ __launch_bounds__(256) void phase_kernel(const float* __restrict__ lin_z,
                                                    const float* __restrict__ bo,
                                                    const float* __restrict__ Gr,
                                                    const float* __restrict__ Gi,
                                                    const float* __restrict__ hrr,
                                                    const float* __restrict__ hri,
                                                    float* __restrict__ accum)
{
  const int b = blockIdx.x;
  const int tid = threadIdx.x;
  __shared__ float lsh[200];
  __shared__ float u[100];
  __shared__ float pp[100];
  __shared__ float redbuf[4];
  if (tid < 200){
    float a = bo[tid];
#pragma unroll 5
    for (int z = 0; z < 25; ++z)
      a += lin_z[((size_t)z*512 + b)*208 + tid];
    lsh[tid] = a;
  }
  __syncthreads();
  if (tid < 100){
    float c = cosf(lsh[tid]);
    float s = sinf(lsh[100 + tid]);
    float hr = hrr[b*100 + tid];
    float hi = hri[b*100 + tid];
    u[tid]  = c*hr - s*hi;
    pp[tid] = c*hi + s*hr;
  }
  __syncthreads();
  const int m = tid;
  const float4* grow  = (const float4*)(Gr + ((size_t)b*256 + m)*100);
  const float4* girow = (const float4*)(Gi + ((size_t)b*256 + m)*100);
  float tr = 0.f, ti = 0.f;
#pragma unroll
  for (int i = 0; i < 25; ++i){
    float4 g  = grow[i];
    float4 gg = girow[i];
    float4 uu = *(const float4*)&u[i*4];
    float4 qq = *(const float4*)&pp[i*4];
    tr += g.x*uu.x - gg.x*qq.x;  ti += g.x*qq.x + gg.x*uu.x;
    tr += g.y*uu.y - gg.y*qq.y;  ti += g.y*qq.y + gg.y*uu.y;
    tr += g.z*uu.z - gg.z*qq.z;  ti += g.z*qq.z + gg.z*uu.z;
    tr += g.w*uu.w - gg.w*qq.w;  ti += g.w*qq.w + gg.w*uu.w;
  }
  float ns = tr*tr + ti*ti;
#pragma unroll
  for (int off = 32; off; off >>= 1) ns += __shfl_down(ns, off);
  if ((tid & 63) == 0) redbuf[tid >> 6] = ns;
  __syncthreads();
  if (tid == 0) atomicAdd(accum, redbuf[0] + redbuf[1] + redbuf[2] + redbuf[3]);
}

__global__ void finalize_kernel(const float* __restrict__ accum, float* __restrict__ out)
{
  out[0] = -accum[0] * (1.0f / 512.0f);
}

extern "C" void kernel_launch(void* const* d_in, const int* in_sizes, int n_in,
                              void* d_out, int out_size, void* d_ws, size_t ws_size,
                              hipStream_t stream)
{
  const float* F   = (const float*)d_in[0];
  const float* Gr  = (const float*)d_in[1];
  const float* Gi  = (const float*)d_in[2];
  const float* hrr = (const float*)d_in[3];
  const float* hri = (const float*)d_in[4];
  const float* W1  = (const float*)d_in[5];
  const float* b1  = (const float*)d_in[6];
  const float* g1  = (const float*)d_in[7];
  const float* be1 = (const float*)d_in[8];
  const float* W2  = (const float*)d_in[9];
  const float* b2  = (const float*)d_in[10];
  const float* g2  = (const float*)d_in[11];
  const float* be2 = (const float*)d_in[12];
  const float* W3  = (const float*)d_in[13];
  const float* b3  = (const float*)d_in[14];
  const float* g3  = (const float*)d_in[15];
  const float* be3 = (const float*)d_in[16];
  const float* W4  = (const float*)d_in[17];
  const float* b4  = (const float*)d_in[18];
  const float* g4  = (const float*)d_in[19];
  const float* be4 = (const float*)d_in[20];
  const float* Wo  = (const float*)d_in[21];
  const float* bo  = (const float*)d_in[22];

  char* ws = (char*)d_ws;
  unsigned short* y1   = (unsigned short*)(ws);
  unsigned short* y2   = (unsigned short*)(ws + 52428800);
  unsigned short* y3   = (unsigned short*)(ws);
  unsigned short* y4   = (unsigned short*)(ws + 52428800);
  unsigned short* Wob  = (unsigned short*)(ws + 65536000);   // 256x12800 bf16
  float*          lin_z= (float*)(ws + 13107200);            // 25x512x208 f32
  float* stats = (float*)(ws + 78643200);
  float* ssb   = (float*)(ws + 78649344);
  float* accum = (float*)(ws + 78653440);
  unsigned short* Wpk2 = (unsigned short*)(ws + 78653456);
  unsigned short* Wpk3 = (unsigned short*)(ws + 78800912);
  unsigned short* Wpk4 = (unsigned short*)(ws + 78874640);

  hipMemsetAsync(ws + 78643200, 0, 10256, stream);

  const float invN = 1.0f / 204800.0f;

  packw_kernel<<<36, 256, 0, stream>>>(W2, Wpk2, 36, 7, 9216);
  packw_kernel<<<18, 256, 0, stream>>>(W3, Wpk3, 18, 6, 4608);
  packw_kernel<<< 9, 256, 0, stream>>>(W4, Wpk4, 18, 6, 2304);

  conv1_kernel<<<dim3(512, 2), 256, 0, stream>>>(F, W1, b1, y1, stats);
  bn_fin<<<1, 128, 0, stream>>>(stats, g1, be1, ssb, 128, invN, 1);

  conv_mfma<128, 64, 5><<<dim3(512, 7), 256, 0, stream>>>(y1, ssb, Wpk2, b2, y2, stats + 256);
  bn_fin<<<1, 64, 0, stream>>>(stats + 256, g2, be2, ssb + 256, 64, invN, 4);

  conv_mfma<64, 64, 8><<<dim3(512, 7), 256, 0, stream>>>(y2, ssb + 256, Wpk3, b3, y3, stats + 768);
  bn_fin<<<1, 64, 0, stream>>>(stats + 768, g3, be3, ssb + 384, 64, invN, 4);

  conv_mfma<64, 32, 8><<<dim3(512, 7), 256, 0, stream>>>(y3, ssb + 384, Wpk4, b4, y4, stats + 1280);
  bn_fin<<<1, 32, 0, stream>>>(stats + 1280, g4, be4, ssb + 512, 32, invN, 4);

  wopack_kernel<<<256, 256, 0, stream>>>(Wo, Wob);

  linear_mfma<<<dim3(8, 4, 25), 256, 0, stream>>>(y4, ssb + 512, Wob, lin_z);

  phase_kernel<<<512, 256, 0, stream>>>(lin_z, bo, Gr, Gi, hrr, hri, accum);
  finalize_kernel<<<1, 1, 0, stream>>>(accum, (float*)d_out);
}

// Round 6
// 292.158 us; speedup vs baseline: 18.8069x; 1.1116x over previous
//
#include <hip/hip_runtime.h>
#include <math.h>

typedef __bf16 bf16x8 __attribute__((ext_vector_type(8)));
typedef float f32x4 __attribute__((ext_vector_type(4)));
typedef unsigned short ushort8 __attribute__((ext_vector_type(8)));

__device__ __forceinline__ float bf2f(unsigned short u){ return __uint_as_float(((unsigned)u) << 16); }
__device__ __forceinline__ unsigned short f2bf(float f){
  unsigned v = __float_as_uint(f);
  return (unsigned short)((v + 0x7FFFu + ((v >> 16) & 1u)) >> 16);
}

// ---------- pack W1 [128][2][3][3] -> A-frag order [ct=8][lane=64][8], k = ci*9+dhw, pad k>=18 ----------
__global__ void packw1_kernel(const float* __restrict__ W1, unsigned short* __restrict__ Wpk1)
{
  int idx = blockIdx.x*256 + threadIdx.x;   // 512 total
  if (idx >= 512) return;
  int lane = idx & 63, ct = idx >> 6;
  int co = ct*16 + (lane & 15);
  int lq = lane >> 4;
#pragma unroll
  for (int j = 0; j < 8; ++j){
    int k = lq*8 + j;
    Wpk1[(size_t)idx*8 + j] = (k < 18) ? f2bf(W1[(size_t)co*18 + k]) : (unsigned short)0;
  }
}

// ================= conv1 v3: 2->128 via single-K MFMA, fused stats =================
// block = 1 image; padded 22x22x2 f32 stage (zero borders -> no masks); 25 px-tiles.
__global__ __launch_bounds__(256, 2) void conv1_mfma(
    const float* __restrict__ F, const unsigned short* __restrict__ Wpk1,
    const float* __restrict__ b1, unsigned short* __restrict__ y1,
    float* __restrict__ stats)
{
  __shared__ float xp[2*484];
  __shared__ float sred[256];
  const int tid = threadIdx.x, b = blockIdx.x;
  const int wid = tid >> 6, lane = tid & 63, lq = lane >> 4, lr = lane & 15;

  for (int i = tid; i < 256; i += 256) sred[i] = 0.f;
  for (int i = tid; i < 968; i += 256) xp[i] = 0.f;
  __syncthreads();
  for (int i = tid; i < 800; i += 256){
    int ci = i / 400, p = i - ci*400;
    xp[ci*484 + (p/20 + 1)*22 + (p%20) + 1] = F[((size_t)b*2 + ci)*400 + p];
  }
  __syncthreads();

  // A-fragments: all 8 cout-tiles resident in VGPRs
  bf16x8 af[8];
#pragma unroll
  for (int ct = 0; ct < 8; ++ct)
    af[ct] = *(const bf16x8*)(Wpk1 + (size_t)(ct*64 + lane)*8);

  // per-lane K geometry: k = lq*8+j -> (ci, dh, dw); valid k<18
  int off[8]; bool kval[8];
#pragma unroll
  for (int j = 0; j < 8; ++j){
    int k = lq*8 + j;
    kval[j] = (k < 18);
    int kc = kval[j] ? k : 0;
    int ci = kc / 9, dhw = kc - ci*9;
    off[j] = ci*484 + (dhw/3)*22 + (dhw - (dhw/3)*3);
  }

  // biases
  f32x4 bias[8];
#pragma unroll
  for (int ct = 0; ct < 8; ++ct)
    bias[ct] = *(const f32x4*)(b1 + ct*16 + lq*4);

  float smv[8][4], sqv[8][4];
#pragma unroll
  for (int ct = 0; ct < 8; ++ct)
#pragma unroll
    for (int r = 0; r < 4; ++r){ smv[ct][r] = 0.f; sqv[ct][r] = 0.f; }

  for (int pt = wid; pt < 25; pt += 4){
    const int px = pt*16 + lr;
    const int h = px/20, w = px - (px/20)*20;
    const int base = h*22 + w;
    union { unsigned short u[8]; bf16x8 h8; } bfr;
#pragma unroll
    for (int j = 0; j < 8; ++j){
      float xv = kval[j] ? xp[base + off[j]] : 0.f;
      bfr.u[j] = f2bf(xv);
    }
    f32x4 zero4 = {0.f,0.f,0.f,0.f};
#pragma unroll
    for (int ct = 0; ct < 8; ++ct){
      f32x4 acc = __builtin_amdgcn_mfma_f32_16x16x32_bf16(af[ct], bfr.h8, zero4, 0, 0, 0);
      f32x4 y = acc + bias[ct];
      union { unsigned short u[4]; unsigned long long ll; } pk;
#pragma unroll
      for (int r = 0; r < 4; ++r){
        pk.u[r] = f2bf(y[r]);
        smv[ct][r] += y[r];
        sqv[ct][r] = fmaf(y[r], y[r], sqv[ct][r]);
      }
      *(unsigned long long*)(y1 + ((size_t)b*400 + px)*128 + ct*16 + lq*4) = pk.ll;
    }
  }

#pragma unroll
  for (int ct = 0; ct < 8; ++ct)
#pragma unroll
    for (int r = 0; r < 4; ++r){
      float v = smv[ct][r], q = sqv[ct][r];
#pragma unroll
      for (int m = 1; m < 16; m <<= 1){ v += __shfl_xor(v, m); q += __shfl_xor(q, m); }
      if (lr == 0){
        int co = ct*16 + lq*4 + r;
        atomicAdd(&sred[co], v);
        atomicAdd(&sred[128 + co], q);
      }
    }
  __syncthreads();
  float* st = stats + (size_t)(b & 3) * 256;
  for (int i = tid; i < 256; i += 256)
    atomicAdd(&st[i], sred[i]);
}

// ---------- fold sliced stats -> per-channel scale/shift ----------
__global__ void bn_fin(const float* __restrict__ stats, const float* __restrict__ g,
                       const float* __restrict__ be, float* __restrict__ ss,
                       int C, float invN, int nsl)
{
  int c = threadIdx.x;
  if (c < C){
    float s = 0.f, q = 0.f;
    for (int t = 0; t < nsl; ++t){ s += stats[t*2*C + c]; q += stats[t*2*C + C + c]; }
    float mean = s * invN;
    float var  = q * invN - mean * mean;
    float sc   = g[c] * rsqrtf(var + 1e-5f);
    ss[c]      = sc;
    ss[C + c]  = be[c] - mean * sc;
  }
}

// ---------- weight pack into MFMA A-fragment order ----------
__global__ void packw_kernel(const float* __restrict__ W, unsigned short* __restrict__ Wpk,
                             int KC, int cin_shift, int total)
{
  int idx = blockIdx.x*256 + threadIdx.x;
  if (idx >= total) return;
  int lane = idx & 63, t2 = idx >> 6;
  int kcg = t2 % KC, ct = t2 / KC;
  int co  = ct*16 + (lane & 15);
  int kg0 = kcg*32 + (lane >> 4)*8;
  int CIN = 1 << cin_shift;
#pragma unroll
  for (int j = 0; j < 8; ++j){
    int kg  = kg0 + j;
    int dhw = kg >> cin_shift;
    int ci  = kg & (CIN-1);
    Wpk[(size_t)idx*8 + j] = f2bf(W[((size_t)co*CIN + ci)*9 + dhw]);
  }
}

// ================= MFMA implicit-GEMM conv 3x3 SAME =================
template<int CIN, int COUT, int NBLK>
__global__ __launch_bounds__(256, NBLK) void conv_mfma(
    const unsigned short* __restrict__ xin, const float* __restrict__ ss_in,
    const unsigned short* __restrict__ Wpk, const float* __restrict__ bconv,
    unsigned short* __restrict__ yout, float* __restrict__ stats)
{
  constexpr int NG   = CIN/8;
  constexpr int LOGNG= (CIN==128) ? 4 : 3;
  constexpr int KC   = (9*CIN)/32;
  constexpr int NSUB = CIN/32;
  constexpr int CT_W = (COUT==64) ? 2 : 1;
  __shared__ unsigned short xs[120*CIN];
  __shared__ float sred[2*COUT];

  const int tid = threadIdx.x;
  const int b = blockIdx.x, t = blockIdx.y;
  const int q0 = t*64;
  const int rb = q0/20 - 1;
  const int wid = tid >> 6, lane = tid & 63, lq = lane >> 4, lr = lane & 15;

  for (int i = tid; i < 2*COUT; i += 256) sred[i] = 0.f;

  {
    const int g = tid & (NG-1);
    const int c = g*8;
    f32x4 s0 = *(const f32x4*)(ss_in + c);
    f32x4 s1 = *(const f32x4*)(ss_in + c + 4);
    f32x4 h0 = *(const f32x4*)(ss_in + CIN + c);
    f32x4 h1 = *(const f32x4*)(ss_in + CIN + c + 4);
    for (int i = tid; i < 120*NG; i += 256){
      int L  = i >> LOGNG;
      int ps = rb*20 + L;
      union { unsigned short u[8]; uint4 v; } pk;
      if (ps >= 0 && ps < 400){
        ushort8 raw = *(const ushort8*)(xin + ((size_t)b*400 + ps)*CIN + c);
        pk.u[0] = f2bf(fmaxf(fmaf(bf2f(raw[0]), s0[0], h0[0]), 0.f));
        pk.u[1] = f2bf(fmaxf(fmaf(bf2f(raw[1]), s0[1], h0[1]), 0.f));
        pk.u[2] = f2bf(fmaxf(fmaf(bf2f(raw[2]), s0[2], h0[2]), 0.f));
        pk.u[3] = f2bf(fmaxf(fmaf(bf2f(raw[3]), s0[3], h0[3]), 0.f));
        pk.u[4] = f2bf(fmaxf(fmaf(bf2f(raw[4]), s1[0], h1[0]), 0.f));
        pk.u[5] = f2bf(fmaxf(fmaf(bf2f(raw[5]), s1[1], h1[1]), 0.f));
        pk.u[6] = f2bf(fmaxf(fmaf(bf2f(raw[6]), s1[2], h1[2]), 0.f));
        pk.u[7] = f2bf(fmaxf(fmaf(bf2f(raw[7]), s1[3], h1[3]), 0.f));
      } else {
        pk.v.x = 0u; pk.v.y = 0u; pk.v.z = 0u; pk.v.w = 0u;
      }
      *(uint4*)&xs[(size_t)((L << LOGNG) + (g ^ (L & 7)))*8] = pk.v;
    }
  }
  __syncthreads();

  const int ct0 = (wid & 1) * CT_W;
  const int pt0 = (wid >> 1) * 2;
  int Lq[2], px[2]; bool mL[2], mR[2];
#pragma unroll
  for (int k2 = 0; k2 < 2; ++k2){
    int q = q0 + (pt0 + k2)*16 + lr;
    px[k2] = q;
    int w  = q % 20;
    mL[k2] = (w == 0); mR[k2] = (w == 19);
    Lq[k2] = q - 20*rb;
  }
  f32x4 acc[CT_W][2];
#pragma unroll
  for (int c2 = 0; c2 < CT_W; ++c2)
#pragma unroll
    for (int k2 = 0; k2 < 2; ++k2){ acc[c2][k2][0]=0.f; acc[c2][k2][1]=0.f; acc[c2][k2][2]=0.f; acc[c2][k2][3]=0.f; }

#pragma unroll 3
  for (int dhw = 0; dhw < 9; ++dhw){
    const int dr = dhw/3 - 1, dc = dhw%3 - 1;
    const int doff = dr*20 + dc;
#pragma unroll
    for (int sub = 0; sub < NSUB; ++sub){
      bf16x8 af[CT_W];
#pragma unroll
      for (int c2 = 0; c2 < CT_W; ++c2)
        af[c2] = *(const bf16x8*)(Wpk + (((size_t)((ct0+c2)*KC + dhw*NSUB + sub)*64 + lane) << 3));
      bf16x8 bf[2];
#pragma unroll
      for (int k2 = 0; k2 < 2; ++k2){
        int Lt = Lq[k2] + doff;
        Lt = Lt < 0 ? 0 : (Lt > 119 ? 119 : Lt);
        int addr = (Lt << LOGNG) + ((sub*4 + lq) ^ (Lt & 7));
        union { uint4 v; bf16x8 h; } u;
        u.h = *(const bf16x8*)&xs[(size_t)addr*8];
        if (dc != 0){
          bool dead = (dc < 0) ? mL[k2] : mR[k2];
          unsigned keep = dead ? 0u : 0xFFFFFFFFu;
          u.v.x &= keep; u.v.y &= keep; u.v.z &= keep; u.v.w &= keep;
        }
        bf[k2] = u.h;
      }
#pragma unroll
      for (int c2 = 0; c2 < CT_W; ++c2)
#pragma unroll
        for (int k2 = 0; k2 < 2; ++k2)
          acc[c2][k2] = __builtin_amdgcn_mfma_f32_16x16x32_bf16(af[c2], bf[k2], acc[c2][k2], 0, 0, 0);
    }
  }

  float smv[CT_W][4], sqv[CT_W][4];
#pragma unroll
  for (int c2 = 0; c2 < CT_W; ++c2)
#pragma unroll
    for (int r = 0; r < 4; ++r){ smv[c2][r] = 0.f; sqv[c2][r] = 0.f; }

#pragma unroll
  for (int c2 = 0; c2 < CT_W; ++c2){
    f32x4 bias = *(const f32x4*)(bconv + (ct0+c2)*16 + lq*4);
#pragma unroll
    for (int k2 = 0; k2 < 2; ++k2){
      bool ok = px[k2] < 400;
      f32x4 y = acc[c2][k2] + bias;
      union { unsigned short u[4]; unsigned long long ll; } pk;
#pragma unroll
      for (int r = 0; r < 4; ++r){
        float yv = ok ? y[r] : 0.f;
        pk.u[r] = f2bf(y[r]);
        smv[c2][r] += yv;
        sqv[c2][r] = fmaf(yv, yv, sqv[c2][r]);
      }
      if (ok)
        *(unsigned long long*)(yout + ((size_t)b*400 + px[k2])*COUT + (ct0+c2)*16 + lq*4) = pk.ll;
    }
  }
#pragma unroll
  for (int c2 = 0; c2 < CT_W; ++c2)
#pragma unroll
    for (int r = 0; r < 4; ++r){
      float v = smv[c2][r], w2 = sqv[c2][r];
#pragma unroll
      for (int m = 1; m < 16; m <<= 1){ v += __shfl_xor(v, m); w2 += __shfl_xor(w2, m); }
      if (lr == 0){
        int co = (ct0+c2)*16 + lq*4 + r;
        atomicAdd(&sred[co], v);
        atomicAdd(&sred[COUT + co], w2);
      }
    }
  __syncthreads();
  float* st = stats + (size_t)(t & 3) * 2 * COUT;
  for (int i = tid; i < 2*COUT; i += 256)
    atomicAdd(&st[i], sred[i]);
}

// ---------- pack/permute Wo[j][c*400+p] -> Wob[j][p*32+c] bf16, rows 200..255 zero ----------
__global__ __launch_bounds__(256) void wopack_kernel(const float* __restrict__ Wo,
                                                     unsigned short* __restrict__ Wob)
{
  __shared__ float row[12800];
  const int j = blockIdx.x, tid = threadIdx.x;
  if (j < 200){
    const float4* src = (const float4*)(Wo + (size_t)j*12800);
    for (int i = tid; i < 3200; i += 256) ((float4*)row)[i] = src[i];
    __syncthreads();
    for (int ko = tid; ko < 1600; ko += 256){
      int p = ko >> 2, c0 = (ko & 3)*8;
      union { unsigned short u[8]; uint4 v; } pk;
#pragma unroll
      for (int t = 0; t < 8; ++t) pk.u[t] = f2bf(row[(c0+t)*400 + p]);
      *(uint4*)(Wob + (size_t)j*12800 + ko*8) = pk.v;
    }
  } else {
    uint4 z = {0,0,0,0};
    for (int ko = tid; ko < 1600; ko += 256)
      *(uint4*)(Wob + (size_t)j*12800 + ko*8) = z;
  }
}

// ================= linear: MFMA split-K, BN+ReLU(y4) fused into A-stage =================
__global__ __launch_bounds__(256, 4) void linear_mfma(
    const unsigned short* __restrict__ y4, const float* __restrict__ ss4,
    const unsigned short* __restrict__ Wob, float* __restrict__ lin_z)
{
  __shared__ unsigned short As[64*128];
  __shared__ unsigned short Bs[64*128];
  const int tid = threadIdx.x;
  const int m0 = blockIdx.x * 64;
  const int j0 = blockIdx.y * 64;
  const int z  = blockIdx.z;
  const int wid = tid >> 6, lane = tid & 63, lq = lane >> 4, lr = lane & 15;
  const int srow = tid >> 4, soct = tid & 15;
  const int c0 = (soct & 3) * 8;

  f32x4 s0 = *(const f32x4*)(ss4 + c0);
  f32x4 s1 = *(const f32x4*)(ss4 + c0 + 4);
  f32x4 h0 = *(const f32x4*)(ss4 + 32 + c0);
  f32x4 h1 = *(const f32x4*)(ss4 + 32 + c0 + 4);

  f32x4 acc[4];
#pragma unroll
  for (int ct = 0; ct < 4; ++ct){ acc[ct][0]=0.f; acc[ct][1]=0.f; acc[ct][2]=0.f; acc[ct][3]=0.f; }

  for (int ch = 0; ch < 4; ++ch){
    const int k0 = z*512 + ch*128;
    __syncthreads();
#pragma unroll
    for (int pass = 0; pass < 4; ++pass){
      int row = pass*16 + srow;
      ushort8 raw = *(const ushort8*)(y4 + (size_t)(m0+row)*12800 + k0 + soct*8);
      union { unsigned short u[8]; uint4 v; } pk;
      pk.u[0] = f2bf(fmaxf(fmaf(bf2f(raw[0]), s0[0], h0[0]), 0.f));
      pk.u[1] = f2bf(fmaxf(fmaf(bf2f(raw[1]), s0[1], h0[1]), 0.f));
      pk.u[2] = f2bf(fmaxf(fmaf(bf2f(raw[2]), s0[2], h0[2]), 0.f));
      pk.u[3] = f2bf(fmaxf(fmaf(bf2f(raw[3]), s0[3], h0[3]), 0.f));
      pk.u[4] = f2bf(fmaxf(fmaf(bf2f(raw[4]), s1[0], h1[0]), 0.f));
      pk.u[5] = f2bf(fmaxf(fmaf(bf2f(raw[5]), s1[1], h1[1]), 0.f));
      pk.u[6] = f2bf(fmaxf(fmaf(bf2f(raw[6]), s1[2], h1[2]), 0.f));
      pk.u[7] = f2bf(fmaxf(fmaf(bf2f(raw[7]), s1[3], h1[3]), 0.f));
      *(uint4*)&As[(size_t)((row << 4) + (soct ^ (row & 7)))*8] = pk.v;
      uint4 wv = *(const uint4*)(Wob + (size_t)(j0+row)*12800 + k0 + soct*8);
      *(uint4*)&Bs[(size_t)((row << 4) + (soct ^ (row & 7)))*8] = wv;
    }
    __syncthreads();
#pragma unroll
    for (int ks = 0; ks < 4; ++ks){
      const int arow = wid*16 + lr;
      bf16x8 afr = *(const bf16x8*)&As[(size_t)((arow << 4) + ((ks*4 + lq) ^ (arow & 7)))*8];
#pragma unroll
      for (int ct = 0; ct < 4; ++ct){
        const int brow = ct*16 + lr;
        bf16x8 bfr = *(const bf16x8*)&Bs[(size_t)((brow << 4) + ((ks*4 + lq) ^ (brow & 7)))*8];
        acc[ct] = __builtin_amdgcn_mfma_f32_16x16x32_bf16(afr, bfr, acc[ct], 0, 0, 0);
      }
    }
  }
#pragma unroll
  for (int ct = 0; ct < 4; ++ct){
    int j = j0 + ct*16 + lr;
    if (j < 208){
#pragma unroll
      for (int r = 0; r < 4; ++r){
        int m = m0 + wid*16 + lq*4 + r;
        lin_z[((size_t)z*512 + m)*208 + j] = acc[ct][r];
      }
    }
  }
}

// ---------- phase + einsum + norm (with fused split-K reduction + bias) ----------
__global__ __launch_bounds__(256) void phase_kernel(const float* __restrict__ lin_z,
                                                    const float* __restrict__ bo,
                                                    const float* __restrict__ Gr,
                                                    const float* __restrict__ Gi,
                                                    const float* __restrict__ hrr,
                                                    const float* __restrict__ hri,
                                                    float* __restrict__ accum)
{
  const int b = blockIdx.x;
  const int tid = threadIdx.x;
  __shared__ float lsh[200];
  __shared__ float u[100];
  __shared__ float pp[100];
  __shared__ float redbuf[4];
  if (tid < 200){
    float a = bo[tid];
#pragma unroll 5
    for (int z = 0; z < 25; ++z)
      a += lin_z[((size_t)z*512 + b)*208 + tid];
    lsh[tid] = a;
  }
  __syncthreads();
  if (tid < 100){
    float c = cosf(lsh[tid]);
    float s = sinf(lsh[100 + tid]);
    float hr = hrr[b*100 + tid];
    float hi = hri[b*100 + tid];
    u[tid]  = c*hr - s*hi;
    pp[tid] = c*hi + s*hr;
  }
  __syncthreads();
  const int m = tid;
  const float4* grow  = (const float4*)(Gr + ((size_t)b*256 + m)*100);
  const float4* girow = (const float4*)(Gi + ((size_t)b*256 + m)*100);
  float tr = 0.f, ti = 0.f;
#pragma unroll
  for (int i = 0; i < 25; ++i){
    float4 g  = grow[i];
    float4 gg = girow[i];
    float4 uu = *(const float4*)&u[i*4];
    float4 qq = *(const float4*)&pp[i*4];
    tr += g.x*uu.x - gg.x*qq.x;  ti += g.x*qq.x + gg.x*uu.x;
    tr += g.y*uu.y - gg.y*qq.y;  ti += g.y*qq.y + gg.y*uu.y;
    tr += g.z*uu.z - gg.z*qq.z;  ti += g.z*qq.z + gg.z*uu.z;
    tr += g.w*uu.w - gg.w*qq.w;  ti += g.w*qq.w + gg.w*uu.w;
  }
  float ns = tr*tr + ti*ti;
#pragma unroll
  for (int off = 32; off; off >>= 1) ns += __shfl_down(ns, off);
  if ((tid & 63) == 0) redbuf[tid >> 6] = ns;
  __syncthreads();
  if (tid == 0) atomicAdd(accum, redbuf[0] + redbuf[1] + redbuf[2] + redbuf[3]);
}

__global__ void finalize_kernel(const float* __restrict__ accum, float* __restrict__ out)
{
  out[0] = -accum[0] * (1.0f / 512.0f);
}

extern "C" void kernel_launch(void* const* d_in, const int* in_sizes, int n_in,
                              void* d_out, int out_size, void* d_ws, size_t ws_size,
                              hipStream_t stream)
{
  const float* F   = (const float*)d_in[0];
  const float* Gr  = (const float*)d_in[1];
  const float* Gi  = (const float*)d_in[2];
  const float* hrr = (const float*)d_in[3];
  const float* hri = (const float*)d_in[4];
  const float* W1  = (const float*)d_in[5];
  const float* b1  = (const float*)d_in[6];
  const float* g1  = (const float*)d_in[7];
  const float* be1 = (const float*)d_in[8];
  const float* W2  = (const float*)d_in[9];
  const float* b2  = (const float*)d_in[10];
  const float* g2  = (const float*)d_in[11];
  const float* be2 = (const float*)d_in[12];
  const float* W3  = (const float*)d_in[13];
  const float* b3  = (const float*)d_in[14];
  const float* g3  = (const float*)d_in[15];
  const float* be3 = (const float*)d_in[16];
  const float* W4  = (const float*)d_in[17];
  const float* b4  = (const float*)d_in[18];
  const float* g4  = (const float*)d_in[19];
  const float* be4 = (const float*)d_in[20];
  const float* Wo  = (const float*)d_in[21];
  const float* bo  = (const float*)d_in[22];

  char* ws = (char*)d_ws;
  unsigned short* y1   = (unsigned short*)(ws);
  unsigned short* y2   = (unsigned short*)(ws + 52428800);
  unsigned short* y3   = (unsigned short*)(ws);
  unsigned short* y4   = (unsigned short*)(ws + 52428800);
  unsigned short* Wob  = (unsigned short*)(ws + 65536000);   // 256x12800 bf16
  float*          lin_z= (float*)(ws + 13107200);            // 25x512x208 f32
  float* stats = (float*)(ws + 78643200);                    // 2304 f32 = 9216 B
  float* ssb   = (float*)(ws + 78652416);                    // 1024 f32 = 4096 B
  float* accum = (float*)(ws + 78656512);                    // 16 B
  unsigned short* Wpk1 = (unsigned short*)(ws + 78656528);   //   8,192
  unsigned short* Wpk2 = (unsigned short*)(ws + 78664720);   // 147,456
  unsigned short* Wpk3 = (unsigned short*)(ws + 78812176);   //  73,728
  unsigned short* Wpk4 = (unsigned short*)(ws + 78885904);   //  36,864

  hipMemsetAsync(ws + 78643200, 0, 13328, stream);  // stats + ssb + accum

  const float invN = 1.0f / 204800.0f;

  packw1_kernel<<<2, 256, 0, stream>>>(W1, Wpk1);
  packw_kernel<<<36, 256, 0, stream>>>(W2, Wpk2, 36, 7, 9216);
  packw_kernel<<<18, 256, 0, stream>>>(W3, Wpk3, 18, 6, 4608);
  packw_kernel<<< 9, 256, 0, stream>>>(W4, Wpk4, 18, 6, 2304);

  conv1_mfma<<<512, 256, 0, stream>>>(F, Wpk1, b1, y1, stats);
  bn_fin<<<1, 128, 0, stream>>>(stats, g1, be1, ssb, 128, invN, 4);

  conv_mfma<128, 64, 5><<<dim3(512, 7), 256, 0, stream>>>(y1, ssb, Wpk2, b2, y2, stats + 1024);
  bn_fin<<<1, 64, 0, stream>>>(stats + 1024, g2, be2, ssb + 256, 64, invN, 4);

  conv_mfma<64, 64, 8><<<dim3(512, 7), 256, 0, stream>>>(y2, ssb + 256, Wpk3, b3, y3, stats + 1536);
  bn_fin<<<1, 64, 0, stream>>>(stats + 1536, g3, be3, ssb + 384, 64, invN, 4);

  conv_mfma<64, 32, 8><<<dim3(512, 7), 256, 0, stream>>>(y3, ssb + 384, Wpk4, b4, y4, stats + 2048);
  bn_fin<<<1, 32, 0, stream>>>(stats + 2048, g4, be4, ssb + 512, 32, invN, 4);

  wopack_kernel<<<256, 256, 0, stream>>>(Wo, Wob);

  linear_mfma<<<dim3(8, 4, 25), 256, 0, stream>>>(y4, ssb + 512, Wob, lin_z);

  phase_kernel<<<512, 256, 0, stream>>>(lin_z, bo, Gr, Gi, hrr, hri, accum);
  finalize_kernel<<<1, 1, 0, stream>>>(accum, (float*)d_out);
}

// Round 7
// 285.398 us; speedup vs baseline: 19.2523x; 1.0237x over previous
//
#include <hip/hip_runtime.h>
#include <math.h>

typedef __bf16 bf16x8 __attribute__((ext_vector_type(8)));
typedef float f32x4 __attribute__((ext_vector_type(4)));
typedef unsigned short ushort8 __attribute__((ext_vector_type(8)));

__device__ __forceinline__ float bf2f(unsigned short u){ return __uint_as_float(((unsigned)u) << 16); }
__device__ __forceinline__ unsigned short f2bf(float f){
  unsigned v = __float_as_uint(f);
  return (unsigned short)((v + 0x7FFFu + ((v >> 16) & 1u)) >> 16);
}

// ---------- pack W1 [128][2][3][3] -> A-frag order [ct=8][lane=64][8], k = ci*9+dhw, pad k>=18 ----------
__global__ void packw1_kernel(const float* __restrict__ W1, unsigned short* __restrict__ Wpk1)
{
  int idx = blockIdx.x*256 + threadIdx.x;   // 512 total
  if (idx >= 512) return;
  int lane = idx & 63, ct = idx >> 6;
  int co = ct*16 + (lane & 15);
  int lq = lane >> 4;
#pragma unroll
  for (int j = 0; j < 8; ++j){
    int k = lq*8 + j;
    Wpk1[(size_t)idx*8 + j] = (k < 18) ? f2bf(W1[(size_t)co*18 + k]) : (unsigned short)0;
  }
}

// ================= conv1: 2->128 via single-K MFMA, fused stats =================
__global__ __launch_bounds__(256, 2) void conv1_mfma(
    const float* __restrict__ F, const unsigned short* __restrict__ Wpk1,
    const float* __restrict__ b1, unsigned short* __restrict__ y1,
    float* __restrict__ stats)
{
  __shared__ float xp[2*484];
  __shared__ float sred[256];
  const int tid = threadIdx.x, b = blockIdx.x;
  const int wid = tid >> 6, lane = tid & 63, lq = lane >> 4, lr = lane & 15;

  for (int i = tid; i < 256; i += 256) sred[i] = 0.f;
  for (int i = tid; i < 968; i += 256) xp[i] = 0.f;
  __syncthreads();
  for (int i = tid; i < 800; i += 256){
    int ci = i / 400, p = i - ci*400;
    xp[ci*484 + (p/20 + 1)*22 + (p%20) + 1] = F[((size_t)b*2 + ci)*400 + p];
  }
  __syncthreads();

  bf16x8 af[8];
#pragma unroll
  for (int ct = 0; ct < 8; ++ct)
    af[ct] = *(const bf16x8*)(Wpk1 + (size_t)(ct*64 + lane)*8);

  int off[8]; bool kval[8];
#pragma unroll
  for (int j = 0; j < 8; ++j){
    int k = lq*8 + j;
    kval[j] = (k < 18);
    int kc = kval[j] ? k : 0;
    int ci = kc / 9, dhw = kc - ci*9;
    off[j] = ci*484 + (dhw/3)*22 + (dhw - (dhw/3)*3);
  }

  f32x4 bias[8];
#pragma unroll
  for (int ct = 0; ct < 8; ++ct)
    bias[ct] = *(const f32x4*)(b1 + ct*16 + lq*4);

  float smv[8][4], sqv[8][4];
#pragma unroll
  for (int ct = 0; ct < 8; ++ct)
#pragma unroll
    for (int r = 0; r < 4; ++r){ smv[ct][r] = 0.f; sqv[ct][r] = 0.f; }

  for (int pt = wid; pt < 25; pt += 4){
    const int px = pt*16 + lr;
    const int h = px/20, w = px - (px/20)*20;
    const int base = h*22 + w;
    union { unsigned short u[8]; bf16x8 h8; } bfr;
#pragma unroll
    for (int j = 0; j < 8; ++j){
      float xv = kval[j] ? xp[base + off[j]] : 0.f;
      bfr.u[j] = f2bf(xv);
    }
    f32x4 zero4 = {0.f,0.f,0.f,0.f};
#pragma unroll
    for (int ct = 0; ct < 8; ++ct){
      f32x4 acc = __builtin_amdgcn_mfma_f32_16x16x32_bf16(af[ct], bfr.h8, zero4, 0, 0, 0);
      f32x4 y = acc + bias[ct];
      union { unsigned short u[4]; unsigned long long ll; } pk;
#pragma unroll
      for (int r = 0; r < 4; ++r){
        pk.u[r] = f2bf(y[r]);
        smv[ct][r] += y[r];
        sqv[ct][r] = fmaf(y[r], y[r], sqv[ct][r]);
      }
      *(unsigned long long*)(y1 + ((size_t)b*400 + px)*128 + ct*16 + lq*4) = pk.ll;
    }
  }

#pragma unroll
  for (int ct = 0; ct < 8; ++ct)
#pragma unroll
    for (int r = 0; r < 4; ++r){
      float v = smv[ct][r], q = sqv[ct][r];
#pragma unroll
      for (int m = 1; m < 16; m <<= 1){ v += __shfl_xor(v, m); q += __shfl_xor(q, m); }
      if (lr == 0){
        int co = ct*16 + lq*4 + r;
        atomicAdd(&sred[co], v);
        atomicAdd(&sred[128 + co], q);
      }
    }
  __syncthreads();
  float* st = stats + (size_t)(b & 3) * 256;
  for (int i = tid; i < 256; i += 256)
    atomicAdd(&st[i], sred[i]);
}

// ---------- fold sliced stats -> per-channel scale/shift ----------
__global__ void bn_fin(const float* __restrict__ stats, const float* __restrict__ g,
                       const float* __restrict__ be, float* __restrict__ ss,
                       int C, float invN, int nsl)
{
  int c = threadIdx.x;
  if (c < C){
    float s = 0.f, q = 0.f;
    for (int t = 0; t < nsl; ++t){ s += stats[t*2*C + c]; q += stats[t*2*C + C + c]; }
    float mean = s * invN;
    float var  = q * invN - mean * mean;
    float sc   = g[c] * rsqrtf(var + 1e-5f);
    ss[c]      = sc;
    ss[C + c]  = be[c] - mean * sc;
  }
}

// ---------- weight pack into MFMA A-fragment order ----------
__global__ void packw_kernel(const float* __restrict__ W, unsigned short* __restrict__ Wpk,
                             int KC, int cin_shift, int total)
{
  int idx = blockIdx.x*256 + threadIdx.x;
  if (idx >= total) return;
  int lane = idx & 63, t2 = idx >> 6;
  int kcg = t2 % KC, ct = t2 / KC;
  int co  = ct*16 + (lane & 15);
  int kg0 = kcg*32 + (lane >> 4)*8;
  int CIN = 1 << cin_shift;
#pragma unroll
  for (int j = 0; j < 8; ++j){
    int kg  = kg0 + j;
    int dhw = kg >> cin_shift;
    int ci  = kg & (CIN-1);
    Wpk[(size_t)idx*8 + j] = f2bf(W[((size_t)co*CIN + ci)*9 + dhw]);
  }
}

// ================= MFMA implicit-GEMM conv 3x3 SAME (v3: padded-22 + reg pipeline) =================
template<int CIN, int COUT, int NBLK>
__global__ __launch_bounds__(256, NBLK) void conv_mfma(
    const unsigned short* __restrict__ xin, const float* __restrict__ ss_in,
    const unsigned short* __restrict__ Wpk, const float* __restrict__ bconv,
    unsigned short* __restrict__ yout, float* __restrict__ stats)
{
  constexpr int NG    = CIN/8;
  constexpr int LOGNG = (CIN==128) ? 4 : 3;
  constexpr int NSUB  = CIN/32;
  constexpr int KC    = 9*NSUB;           // also NSTEP
  constexpr int NSTEP = 9*NSUB;
  constexpr int CT_W  = COUT/32;
  constexpr int NSLOT = 132;              // 6 rows x 22 padded cols
  __shared__ unsigned short xs[NSLOT*CIN];
  __shared__ float sred[2*COUT];

  const int tid = threadIdx.x;
  const int b = blockIdx.x, t = blockIdx.y;
  const int q0 = t*64;
  const int rb = q0/20 - 1;               // first staged image row
  const int wid = tid >> 6, lane = tid & 63, lq = lane >> 4, lr = lane & 15;

  for (int i = tid; i < 2*COUT; i += 256) sred[i] = 0.f;

  // ---- stage 6 rows x 22 cols (halo zero), BN+ReLU fused, octet XOR swizzle ----
  {
    const int g = tid & (NG-1);
    const int c = g*8;
    f32x4 s0 = *(const f32x4*)(ss_in + c);
    f32x4 s1 = *(const f32x4*)(ss_in + c + 4);
    f32x4 h0 = *(const f32x4*)(ss_in + CIN + c);
    f32x4 h1 = *(const f32x4*)(ss_in + CIN + c + 4);
    for (int i = tid; i < NSLOT*NG; i += 256){
      int L  = i >> LOGNG;
      int rl = L / 22, c22 = L - rl*22;
      int col = c22 - 1;
      int row = rb + rl;
      union { unsigned short u[8]; uint4 v; } pk;
      if ((unsigned)col < 20u && (unsigned)row < 20u){
        int ps = row*20 + col;
        ushort8 raw = *(const ushort8*)(xin + ((size_t)b*400 + ps)*CIN + c);
        pk.u[0] = f2bf(fmaxf(fmaf(bf2f(raw[0]), s0[0], h0[0]), 0.f));
        pk.u[1] = f2bf(fmaxf(fmaf(bf2f(raw[1]), s0[1], h0[1]), 0.f));
        pk.u[2] = f2bf(fmaxf(fmaf(bf2f(raw[2]), s0[2], h0[2]), 0.f));
        pk.u[3] = f2bf(fmaxf(fmaf(bf2f(raw[3]), s0[3], h0[3]), 0.f));
        pk.u[4] = f2bf(fmaxf(fmaf(bf2f(raw[4]), s1[0], h1[0]), 0.f));
        pk.u[5] = f2bf(fmaxf(fmaf(bf2f(raw[5]), s1[1], h1[1]), 0.f));
        pk.u[6] = f2bf(fmaxf(fmaf(bf2f(raw[6]), s1[2], h1[2]), 0.f));
        pk.u[7] = f2bf(fmaxf(fmaf(bf2f(raw[7]), s1[3], h1[3]), 0.f));
      } else {
        pk.v.x = 0u; pk.v.y = 0u; pk.v.z = 0u; pk.v.w = 0u;
      }
      *(uint4*)&xs[(size_t)((L << LOGNG) + (g ^ (L & 7)))*8] = pk.v;
    }
  }
  __syncthreads();

  // ---- wave tiling ----
  const int ct0 = (wid & 1) * CT_W;
  const int pt0 = (wid >> 1) * 2;
  int Lb[2], px[2];
#pragma unroll
  for (int k2 = 0; k2 < 2; ++k2){
    int q = q0 + (pt0 + k2)*16 + lr;
    px[k2] = q;
    int row = q/20, col = q - row*20;
    Lb[k2] = (row - rb)*22 + col + 1;
  }
  f32x4 acc[CT_W][2];
#pragma unroll
  for (int c2 = 0; c2 < CT_W; ++c2)
#pragma unroll
    for (int k2 = 0; k2 < 2; ++k2){ acc[c2][k2][0]=0.f; acc[c2][k2][1]=0.f; acc[c2][k2][2]=0.f; acc[c2][k2][3]=0.f; }

  // ---- K loop: 2-deep register ping-pong pipeline, no barriers, no masks ----
  auto LD = [&](int st, bf16x8 (&af)[CT_W], bf16x8 (&bf)[2]){
    int dhw = st / NSUB, sub = st - (st/NSUB)*NSUB;
    int doff = (dhw/3 - 1)*22 + (dhw - (dhw/3)*3 - 1);
#pragma unroll
    for (int c2 = 0; c2 < CT_W; ++c2)
      af[c2] = *(const bf16x8*)(Wpk + (((size_t)((ct0+c2)*KC + st)*64 + lane) << 3));
#pragma unroll
    for (int k2 = 0; k2 < 2; ++k2){
      int Lt = Lb[k2] + doff;
      bf[k2] = *(const bf16x8*)&xs[(size_t)((Lt << LOGNG) + ((sub*4 + lq) ^ (Lt & 7)))*8];
    }
  };
  auto FM = [&](bf16x8 (&af)[CT_W], bf16x8 (&bf)[2]){
#pragma unroll
    for (int c2 = 0; c2 < CT_W; ++c2)
#pragma unroll
      for (int k2 = 0; k2 < 2; ++k2)
        acc[c2][k2] = __builtin_amdgcn_mfma_f32_16x16x32_bf16(af[c2], bf[k2], acc[c2][k2], 0, 0, 0);
  };

  bf16x8 afA[CT_W], bfA[2], afB[CT_W], bfB[2];
  LD(0, afA, bfA);
#pragma unroll
  for (int s2 = 0; s2 < NSTEP/2; ++s2){
    LD(2*s2 + 1, afB, bfB);
    FM(afA, bfA);
    if (2*s2 + 2 < NSTEP) LD(2*s2 + 2, afA, bfA);
    FM(afB, bfB);
  }

  // ---- epilogue ----
  float smv[CT_W][4], sqv[CT_W][4];
#pragma unroll
  for (int c2 = 0; c2 < CT_W; ++c2)
#pragma unroll
    for (int r = 0; r < 4; ++r){ smv[c2][r] = 0.f; sqv[c2][r] = 0.f; }

#pragma unroll
  for (int c2 = 0; c2 < CT_W; ++c2){
    f32x4 bias = *(const f32x4*)(bconv + (ct0+c2)*16 + lq*4);
#pragma unroll
    for (int k2 = 0; k2 < 2; ++k2){
      bool ok = px[k2] < 400;
      f32x4 y = acc[c2][k2] + bias;
      union { unsigned short u[4]; unsigned long long ll; } pk;
#pragma unroll
      for (int r = 0; r < 4; ++r){
        float yv = ok ? y[r] : 0.f;
        pk.u[r] = f2bf(y[r]);
        smv[c2][r] += yv;
        sqv[c2][r] = fmaf(yv, yv, sqv[c2][r]);
      }
      if (ok)
        *(unsigned long long*)(yout + ((size_t)b*400 + px[k2])*COUT + (ct0+c2)*16 + lq*4) = pk.ll;
    }
  }
#pragma unroll
  for (int c2 = 0; c2 < CT_W; ++c2)
#pragma unroll
    for (int r = 0; r < 4; ++r){
      float v = smv[c2][r], w2 = sqv[c2][r];
#pragma unroll
      for (int m = 1; m < 16; m <<= 1){ v += __shfl_xor(v, m); w2 += __shfl_xor(w2, m); }
      if (lr == 0){
        int co = (ct0+c2)*16 + lq*4 + r;
        atomicAdd(&sred[co], v);
        atomicAdd(&sred[COUT + co], w2);
      }
    }
  __syncthreads();
  float* st = stats + (size_t)(t & 3) * 2 * COUT;
  for (int i = tid; i < 2*COUT; i += 256)
    atomicAdd(&st[i], sred[i]);
}

// ---------- pack/permute Wo[j][c*400+p] -> Wob[j][p*32+c] bf16, rows 200..255 zero ----------
__global__ __launch_bounds__(256) void wopack_kernel(const float* __restrict__ Wo,
                                                     unsigned short* __restrict__ Wob)
{
  __shared__ float row[12800];
  const int j = blockIdx.x, tid = threadIdx.x;
  if (j < 200){
    const float4* src = (const float4*)(Wo + (size_t)j*12800);
    for (int i = tid; i < 3200; i += 256) ((float4*)row)[i] = src[i];
    __syncthreads();
    for (int ko = tid; ko < 1600; ko += 256){
      int p = ko >> 2, c0 = (ko & 3)*8;
      union { unsigned short u[8]; uint4 v; } pk;
#pragma unroll
      for (int t = 0; t < 8; ++t) pk.u[t] = f2bf(row[(c0+t)*400 + p]);
      *(uint4*)(Wob + (size_t)j*12800 + ko*8) = pk.v;
    }
  } else {
    uint4 z = {0,0,0,0};
    for (int ko = tid; ko < 1600; ko += 256)
      *(uint4*)(Wob + (size_t)j*12800 + ko*8) = z;
  }
}

// ================= linear: MFMA split-K, BN+ReLU(y4) fused into A-stage =================
__global__ __launch_bounds__(256, 4) void linear_mfma(
    const unsigned short* __restrict__ y4, const float* __restrict__ ss4,
    const unsigned short* __restrict__ Wob, float* __restrict__ lin_z)
{
  __shared__ unsigned short As[64*128];
  __shared__ unsigned short Bs[64*128];
  const int tid = threadIdx.x;
  const int m0 = blockIdx.x * 64;
  const int j0 = blockIdx.y * 64;
  const int z  = blockIdx.z;
  const int wid = tid >> 6, lane = tid & 63, lq = lane >> 4, lr = lane & 15;
  const int srow = tid >> 4, soct = tid & 15;
  const int c0 = (soct & 3) * 8;

  f32x4 s0 = *(const f32x4*)(ss4 + c0);
  f32x4 s1 = *(const f32x4*)(ss4 + c0 + 4);
  f32x4 h0 = *(const f32x4*)(ss4 + 32 + c0);
  f32x4 h1 = *(const f32x4*)(ss4 + 32 + c0 + 4);

  f32x4 acc[4];
#pragma unroll
  for (int ct = 0; ct < 4; ++ct){ acc[ct][0]=0.f; acc[ct][1]=0.f; acc[ct][2]=0.f; acc[ct][3]=0.f; }

  for (int ch = 0; ch < 4; ++ch){
    const int k0 = z*512 + ch*128;
    __syncthreads();
#pragma unroll
    for (int pass = 0; pass < 4; ++pass){
      int row = pass*16 + srow;
      ushort8 raw = *(const ushort8*)(y4 + (size_t)(m0+row)*12800 + k0 + soct*8);
      union { unsigned short u[8]; uint4 v; } pk;
      pk.u[0] = f2bf(fmaxf(fmaf(bf2f(raw[0]), s0[0], h0[0]), 0.f));
      pk.u[1] = f2bf(fmaxf(fmaf(bf2f(raw[1]), s0[1], h0[1]), 0.f));
      pk.u[2] = f2bf(fmaxf(fmaf(bf2f(raw[2]), s0[2], h0[2]), 0.f));
      pk.u[3] = f2bf(fmaxf(fmaf(bf2f(raw[3]), s0[3], h0[3]), 0.f));
      pk.u[4] = f2bf(fmaxf(fmaf(bf2f(raw[4]), s1[0], h1[0]), 0.f));
      pk.u[5] = f2bf(fmaxf(fmaf(bf2f(raw[5]), s1[1], h1[1]), 0.f));
      pk.u[6] = f2bf(fmaxf(fmaf(bf2f(raw[6]), s1[2], h1[2]), 0.f));
      pk.u[7] = f2bf(fmaxf(fmaf(bf2f(raw[7]), s1[3], h1[3]), 0.f));
      *(uint4*)&As[(size_t)((row << 4) + (soct ^ (row & 7)))*8] = pk.v;
      uint4 wv = *(const uint4*)(Wob + (size_t)(j0+row)*12800 + k0 + soct*8);
      *(uint4*)&Bs[(size_t)((row << 4) + (soct ^ (row & 7)))*8] = wv;
    }
    __syncthreads();
#pragma unroll
    for (int ks = 0; ks < 4; ++ks){
      const int arow = wid*16 + lr;
      bf16x8 afr = *(const bf16x8*)&As[(size_t)((arow << 4) + ((ks*4 + lq) ^ (arow & 7)))*8];
#pragma unroll
      for (int ct = 0; ct < 4; ++ct){
        const int brow = ct*16 + lr;
        bf16x8 bfr = *(const bf16x8*)&Bs[(size_t)((brow << 4) + ((ks*4 + lq) ^ (brow & 7)))*8];
        acc[ct] = __builtin_amdgcn_mfma_f32_16x16x32_bf16(afr, bfr, acc[ct], 0, 0, 0);
      }
    }
  }
#pragma unroll
  for (int ct = 0; ct < 4; ++ct){
    int j = j0 + ct*16 + lr;
    if (j < 208){
#pragma unroll
      for (int r = 0; r < 4; ++r){
        int m = m0 + wid*16 + lq*4 + r;
        lin_z[((size_t)z*512 + m)*208 + j] = acc[ct][r];
      }
    }
  }
}

// ---------- phase + einsum + norm (with fused split-K reduction + bias) ----------
__global__ __launch_bounds__(256) void phase_kernel(const float* __restrict__ lin_z,
                                                    const float* __restrict__ bo,
                                                    const float* __restrict__ Gr,
                                                    const float* __restrict__ Gi,
                                                    const float* __restrict__ hrr,
                                                    const float* __restrict__ hri,
                                                    float* __restrict__ accum)
{
  const int b = blockIdx.x;
  const int tid = threadIdx.x;
  __shared__ float lsh[200];
  __shared__ float u[100];
  __shared__ float pp[100];
  __shared__ float redbuf[4];
  if (tid < 200){
    float a = bo[tid];
#pragma unroll 5
    for (int z = 0; z < 25; ++z)
      a += lin_z[((size_t)z*512 + b)*208 + tid];
    lsh[tid] = a;
  }
  __syncthreads();
  if (tid < 100){
    float c = cosf(lsh[tid]);
    float s = sinf(lsh[100 + tid]);
    float hr = hrr[b*100 + tid];
    float hi = hri[b*100 + tid];
    u[tid]  = c*hr - s*hi;
    pp[tid] = c*hi + s*hr;
  }
  __syncthreads();
  const int m = tid;
  const float4* grow  = (const float4*)(Gr + ((size_t)b*256 + m)*100);
  const float4* girow = (const float4*)(Gi + ((size_t)b*256 + m)*100);
  float tr = 0.f, ti = 0.f;
#pragma unroll
  for (int i = 0; i < 25; ++i){
    float4 g  = grow[i];
    float4 gg = girow[i];
    float4 uu = *(const float4*)&u[i*4];
    float4 qq = *(const float4*)&pp[i*4];
    tr += g.x*uu.x - gg.x*qq.x;  ti += g.x*qq.x + gg.x*uu.x;
    tr += g.y*uu.y - gg.y*qq.y;  ti += g.y*qq.y + gg.y*uu.y;
    tr += g.z*uu.z - gg.z*qq.z;  ti += g.z*qq.z + gg.z*uu.z;
    tr += g.w*uu.w - gg.w*qq.w;  ti += g.w*qq.w + gg.w*uu.w;
  }
  float ns = tr*tr + ti*ti;
#pragma unroll
  for (int off = 32; off; off >>= 1) ns += __shfl_down(ns, off);
  if ((tid & 63) == 0) redbuf[tid >> 6] = ns;
  __syncthreads();
  if (tid == 0) atomicAdd(accum, redbuf[0] + redbuf[1] + redbuf[2] + redbuf[3]);
}

__global__ void finalize_kernel(const float* __restrict__ accum, float* __restrict__ out)
{
  out[0] = -accum[0] * (1.0f / 512.0f);
}

extern "C" void kernel_launch(void* const* d_in, const int* in_sizes, int n_in,
                              void* d_out, int out_size, void* d_ws, size_t ws_size,
                              hipStream_t stream)
{
  const float* F   = (const float*)d_in[0];
  const float* Gr  = (const float*)d_in[1];
  const float* Gi  = (const float*)d_in[2];
  const float* hrr = (const float*)d_in[3];
  const float* hri = (const float*)d_in[4];
  const float* W1  = (const float*)d_in[5];
  const float* b1  = (const float*)d_in[6];
  const float* g1  = (const float*)d_in[7];
  const float* be1 = (const float*)d_in[8];
  const float* W2  = (const float*)d_in[9];
  const float* b2  = (const float*)d_in[10];
  const float* g2  = (const float*)d_in[11];
  const float* be2 = (const float*)d_in[12];
  const float* W3  = (const float*)d_in[13];
  const float* b3  = (const float*)d_in[14];
  const float* g3  = (const float*)d_in[15];
  const float* be3 = (const float*)d_in[16];
  const float* W4  = (const float*)d_in[17];
  const float* b4  = (const float*)d_in[18];
  const float* g4  = (const float*)d_in[19];
  const float* be4 = (const float*)d_in[20];
  const float* Wo  = (const float*)d_in[21];
  const float* bo  = (const float*)d_in[22];

  char* ws = (char*)d_ws;
  unsigned short* y1   = (unsigned short*)(ws);
  unsigned short* y2   = (unsigned short*)(ws + 52428800);
  unsigned short* y3   = (unsigned short*)(ws);
  unsigned short* y4   = (unsigned short*)(ws + 52428800);
  unsigned short* Wob  = (unsigned short*)(ws + 65536000);   // 256x12800 bf16
  float*          lin_z= (float*)(ws + 13107200);            // 25x512x208 f32
  float* stats = (float*)(ws + 78643200);                    // 2304 f32
  float* ssb   = (float*)(ws + 78652416);                    // 1024 f32
  float* accum = (float*)(ws + 78656512);                    // 16 B
  unsigned short* Wpk1 = (unsigned short*)(ws + 78656528);
  unsigned short* Wpk2 = (unsigned short*)(ws + 78664720);
  unsigned short* Wpk3 = (unsigned short*)(ws + 78812176);
  unsigned short* Wpk4 = (unsigned short*)(ws + 78885904);

  hipMemsetAsync(ws + 78643200, 0, 13328, stream);

  const float invN = 1.0f / 204800.0f;

  packw1_kernel<<<2, 256, 0, stream>>>(W1, Wpk1);
  packw_kernel<<<36, 256, 0, stream>>>(W2, Wpk2, 36, 7, 9216);
  packw_kernel<<<18, 256, 0, stream>>>(W3, Wpk3, 18, 6, 4608);
  packw_kernel<<< 9, 256, 0, stream>>>(W4, Wpk4, 18, 6, 2304);

  conv1_mfma<<<512, 256, 0, stream>>>(F, Wpk1, b1, y1, stats);
  bn_fin<<<1, 128, 0, stream>>>(stats, g1, be1, ssb, 128, invN, 4);

  conv_mfma<128, 64, 4><<<dim3(512, 7), 256, 0, stream>>>(y1, ssb, Wpk2, b2, y2, stats + 1024);
  bn_fin<<<1, 64, 0, stream>>>(stats + 1024, g2, be2, ssb + 256, 64, invN, 4);

  conv_mfma<64, 64, 6><<<dim3(512, 7), 256, 0, stream>>>(y2, ssb + 256, Wpk3, b3, y3, stats + 1536);
  bn_fin<<<1, 64, 0, stream>>>(stats + 1536, g3, be3, ssb + 384, 64, invN, 4);

  conv_mfma<64, 32, 6><<<dim3(512, 7), 256, 0, stream>>>(y3, ssb + 384, Wpk4, b4, y4, stats + 2048);
  bn_fin<<<1, 32, 0, stream>>>(stats + 2048, g4, be4, ssb + 512, 32, invN, 4);

  wopack_kernel<<<256, 256, 0, stream>>>(Wo, Wob);

  linear_mfma<<<dim3(8, 4, 25), 256, 0, stream>>>(y4, ssb + 512, Wob, lin_z);

  phase_kernel<<<512, 256, 0, stream>>>(lin_z, bo, Gr, Gi, hrr, hri, accum);
  finalize_kernel<<<1, 1, 0, stream>>>(accum, (float*)d_out);
}